// Round 7
// baseline (1571.039 us; speedup 1.0000x reference)
//
#include <hip/hip_runtime.h>
#include <hip/hip_bf16.h>
#include <math.h>
#include <stdint.h>

#define BB 4
#define TT 1024
#define EE 1024
#define HH 16
#define SS 64
#define NEGV -1000000000.0f
#define TR 32
#define TC 32

// ---------------------------------------------------------------------------
// Kernel 1: q/k/v projection.  q[b,h,t,o] = sum_i x[b,t,h*64+i] * Wq[o,i]
// k pre-scaled by 1/32 (= 1/scale^2).
// ---------------------------------------------------------------------------
__global__ __launch_bounds__(256) void qkv_kernel(
    const float* __restrict__ x, const float* __restrict__ Wq,
    const float* __restrict__ Wk, const float* __restrict__ Wv,
    float* __restrict__ q, float* __restrict__ k, float* __restrict__ v)
{
    __shared__ __align__(16) float xs[EE];
    __shared__ __align__(16) float Wl[3][SS][68];
    const int bt  = blockIdx.x;
    const int bb  = bt >> 10;
    const int tt  = bt & 1023;
    const int tid = threadIdx.x;

    const float* xrow = x + (size_t)bt * EE;
    for (int i = tid; i < EE; i += 256) xs[i] = xrow[i];
    for (int i = tid; i < 3 * SS * SS; i += 256) {
        int m = i >> 12;
        int r = (i >> 6) & 63;
        int c = i & 63;
        const float* W = (m == 0) ? Wq : (m == 1) ? Wk : Wv;
        Wl[m][r][c] = W[r * 64 + c];
    }
    __syncthreads();

    const int o = tid & 63;
    const int g = tid >> 6;
    float acc[3][4];
#pragma unroll
    for (int m = 0; m < 3; m++)
#pragma unroll
        for (int t4 = 0; t4 < 4; t4++) acc[m][t4] = 0.f;

    const float4* xs4 = (const float4*)xs;
#pragma unroll
    for (int d4 = 0; d4 < 16; d4++) {
        float4 w[3];
#pragma unroll
        for (int m = 0; m < 3; m++) w[m] = *(const float4*)&Wl[m][o][d4 * 4];
#pragma unroll
        for (int t4 = 0; t4 < 4; t4++) {
            const int hh = g + 4 * t4;
            const float4 xv = xs4[hh * 16 + d4];
#pragma unroll
            for (int m = 0; m < 3; m++)
                acc[m][t4] += xv.x * w[m].x + xv.y * w[m].y + xv.z * w[m].z + xv.w * w[m].w;
        }
    }
#pragma unroll
    for (int m = 0; m < 3; m++) {
        float* dst = (m == 0) ? q : (m == 1) ? k : v;
        const float sc = (m == 1) ? 0.03125f : 1.0f;
#pragma unroll
        for (int t4 = 0; t4 < 4; t4++) {
            const int hh = g + 4 * t4;
            dst[(((size_t)bb * HH + hh) * TT + tt) * SS + o] = acc[m][t4] * sc;
        }
    }
}

// ---------------------------------------------------------------------------
// Kernel 2: vmean (padded-row uniform-softmax output)
// ---------------------------------------------------------------------------
__global__ __launch_bounds__(256) void vmean_kernel(
    const float* __restrict__ v, float* __restrict__ vmean)
{
    const int bh  = blockIdx.x;
    const int tid = threadIdx.x;
    const int d   = tid & 63;
    const int jg  = tid >> 6;
    const float* vb = v + (size_t)bh * TT * SS;
    float p = 0.f;
    for (int j = jg; j < TT; j += 4) p += vb[j * SS + d];
    __shared__ float red[4][64];
    red[jg][d] = p;
    __syncthreads();
    if (jg == 0)
        vmean[bh * SS + d] = (red[0][d] + red[1][d] + red[2][d] + red[3][d]) * (1.0f / TT);
}

// ---------------------------------------------------------------------------
// Kernel 3: flash attention with relative positions (verified logic).
// EPILOGUE WRITES THE REFERENCE'S SCRAMBLED LAYOUT:
//   einsum output is (b,t,h,s); transpose(0,2,1,3)->(b,h,t,s); reshape(b,t,e)
//   => M[b, 64h + (t>>4), 64*(t&15) + s] = attnout[b,h,t,s]
// ---------------------------------------------------------------------------
__global__ __launch_bounds__(256) void attn_kernel(
    const float* __restrict__ q, const float* __restrict__ k,
    const float* __restrict__ v, const float* __restrict__ Er,
    const int* __restrict__ mask, const float* __restrict__ vmean,
    float* __restrict__ attn)
{
    __shared__ __align__(16) float Qs[TR][68];
    __shared__ __align__(16) float Ks[TC][68];
    __shared__ __align__(16) float Vs[TC][68];
    __shared__ __align__(16) float Es[TR + TC - 1][68];
    __shared__ __align__(16) float Ps[TR][36];
    __shared__ float mrow[TR], lrow[TR], arow[TR];

    const int tid = threadIdx.x;
    const int bh  = blockIdx.y;
    const int bb  = bh >> 4;
    const int hh  = bh & 15;
    const int i0  = blockIdx.x * TR;

    const float* qb = q + (size_t)bh * TT * SS;
    const float* kb = k + (size_t)bh * TT * SS;
    const float* vb = v + (size_t)bh * TT * SS;
    const float* Eh = Er + (size_t)hh * TT * SS;

    for (int idx = tid; idx < TR * SS; idx += 256) {
        int r = idx >> 6, d = idx & 63;
        Qs[r][d] = qb[(size_t)(i0 + r) * SS + d];
    }
    if (tid < TR) { mrow[tid] = -1e30f; lrow[tid] = 0.f; }

    const int d0 = (tid & 15) * 4;
    const int rw = tid >> 4;
    float acc0[4] = {0, 0, 0, 0}, acc1[4] = {0, 0, 0, 0};

    const int sc = tid & 31;
    const int r0 = (tid >> 5) * 4;

    for (int j0 = 0; j0 <= i0; j0 += TC) {
        __syncthreads();
        for (int idx = tid; idx < TC * SS; idx += 256) {
            int c = idx >> 6, d = idx & 63;
            Ks[c][d] = kb[(size_t)(j0 + c) * SS + d];
            Vs[c][d] = vb[(size_t)(j0 + c) * SS + d];
        }
        const int lbase = TT - TR - i0 + j0;
        for (int idx = tid; idx < (TR + TC - 1) * SS; idx += 256) {
            int n = idx >> 6, d = idx & 63;
            int l = lbase + n;
            Es[n][d] = (l < TT) ? Eh[(size_t)l * SS + d] : 0.f;
        }
        __syncthreads();

#pragma unroll
        for (int rr = 0; rr < 4; rr++) {
            const int r = r0 + rr;
            const int i = i0 + r, j = j0 + sc;
            float s;
            if (j > i) {
                s = NEGV;
            } else {
                const float4* Q4 = (const float4*)&Qs[r][0];
                const float4* K4 = (const float4*)&Ks[sc][0];
                const float4* E4 = (const float4*)&Es[TR - 1 - r + sc][0];
                float a = 0.f;
#pragma unroll
                for (int dd = 0; dd < 16; dd++) {
                    const float4 qv = Q4[dd], kv = K4[dd], ev = E4[dd];
                    a += qv.x * (kv.x + ev.x) + qv.y * (kv.y + ev.y)
                       + qv.z * (kv.z + ev.z) + qv.w * (kv.w + ev.w);
                }
                s = a;
            }
            Ps[r][sc] = s;
        }
        __syncthreads();

        if (tid < TR) {
            const int r = tid;
            float tmax = -1e30f;
            for (int c = 0; c < TC; c++) tmax = fmaxf(tmax, Ps[r][c]);
            const float newm = fmaxf(mrow[r], tmax);
            const float a = __expf(mrow[r] - newm);
            float psum = 0.f;
            for (int c = 0; c < TC; c++) {
                const float e = __expf(Ps[r][c] - newm);
                Ps[r][c] = e;
                psum += e;
            }
            lrow[r] = lrow[r] * a + psum;
            mrow[r] = newm;
            arow[r] = a;
        }
        __syncthreads();

        const float a0 = arow[rw * 2], a1 = arow[rw * 2 + 1];
#pragma unroll
        for (int t4 = 0; t4 < 4; t4++) { acc0[t4] *= a0; acc1[t4] *= a1; }
#pragma unroll
        for (int c4 = 0; c4 < TC / 4; c4++) {
            const float4 p0 = *(const float4*)&Ps[rw * 2][c4 * 4];
            const float4 p1 = *(const float4*)&Ps[rw * 2 + 1][c4 * 4];
#pragma unroll
            for (int cc = 0; cc < 4; cc++) {
                const float4 vv = *(const float4*)&Vs[c4 * 4 + cc][d0];
                const float pc0 = (cc == 0) ? p0.x : (cc == 1) ? p0.y : (cc == 2) ? p0.z : p0.w;
                const float pc1 = (cc == 0) ? p1.x : (cc == 1) ? p1.y : (cc == 2) ? p1.z : p1.w;
                acc0[0] += pc0 * vv.x; acc0[1] += pc0 * vv.y;
                acc0[2] += pc0 * vv.z; acc0[3] += pc0 * vv.w;
                acc1[0] += pc1 * vv.x; acc1[1] += pc1 * vv.y;
                acc1[2] += pc1 * vv.z; acc1[3] += pc1 * vv.w;
            }
        }
    }
    __syncthreads();

    // epilogue: divide by l, padded-row override, store SCRAMBLED layout:
    // M[b, 64*hh + (t>>4), 64*(t&15) + s]
    const int r_a = rw * 2, r_b = rw * 2 + 1;
    const int i_a = i0 + r_a, i_b = i0 + r_b;
    const float inv0 = 1.0f / lrow[r_a];
    const float inv1 = 1.0f / lrow[r_b];
    const bool pad0 = (mask[bb * TT + i_a] == 0);
    const bool pad1 = (mask[bb * TT + i_b] == 0);
    const float* vm = vmean + bh * SS + d0;
    float4 o0, o1;
    o0.x = pad0 ? vm[0] : acc0[0] * inv0;
    o0.y = pad0 ? vm[1] : acc0[1] * inv0;
    o0.z = pad0 ? vm[2] : acc0[2] * inv0;
    o0.w = pad0 ? vm[3] : acc0[3] * inv0;
    o1.x = pad1 ? vm[0] : acc1[0] * inv1;
    o1.y = pad1 ? vm[1] : acc1[1] * inv1;
    o1.z = pad1 ? vm[2] : acc1[2] * inv1;
    o1.w = pad1 ? vm[3] : acc1[3] * inv1;
    const size_t rowA = (size_t)bb * TT + hh * 64 + (i_a >> 4);
    const size_t rowB = (size_t)bb * TT + hh * 64 + (i_b >> 4);
    *(float4*)(attn + rowA * EE + (i_a & 15) * 64 + d0) = o0;
    *(float4*)(attn + rowB * EE + (i_b & 15) * 64 + d0) = o1;
}

// ---------------------------------------------------------------------------
// Kernel 4: out = M @ Wo^T + bo   (M is the scrambled pre-proj matrix)
// ---------------------------------------------------------------------------
__global__ __launch_bounds__(256) void outproj_kernel(
    const float* __restrict__ A, const float* __restrict__ Wo,
    const float* __restrict__ bo, float* __restrict__ out)
{
    __shared__ __align__(16) float As[64][36];
    __shared__ __align__(16) float Ws[64][36];
    const int tid = threadIdx.x;
    const int o0  = blockIdx.x * 64;
    const int n0  = blockIdx.y * 64;
    const int tx  = tid & 15;
    const int ty  = tid >> 4;

    float acc[4][4];
#pragma unroll
    for (int ii = 0; ii < 4; ii++)
#pragma unroll
        for (int jj = 0; jj < 4; jj++) acc[ii][jj] = 0.f;

    for (int k0 = 0; k0 < 1024; k0 += 32) {
        __syncthreads();
        for (int idx = tid; idx < 2048; idx += 256) {
            int r = idx >> 5, kk = idx & 31;
            As[r][kk] = A[(size_t)(n0 + r) * 1024 + k0 + kk];
            Ws[r][kk] = Wo[(size_t)(o0 + r) * 1024 + k0 + kk];
        }
        __syncthreads();
#pragma unroll
        for (int k4 = 0; k4 < 8; k4++) {
            float4 av[4], wv[4];
#pragma unroll
            for (int ii = 0; ii < 4; ii++) av[ii] = *(const float4*)&As[ty + 16 * ii][k4 * 4];
#pragma unroll
            for (int jj = 0; jj < 4; jj++) wv[jj] = *(const float4*)&Ws[tx + 16 * jj][k4 * 4];
#pragma unroll
            for (int ii = 0; ii < 4; ii++)
#pragma unroll
                for (int jj = 0; jj < 4; jj++)
                    acc[ii][jj] += av[ii].x * wv[jj].x + av[ii].y * wv[jj].y
                                 + av[ii].z * wv[jj].z + av[ii].w * wv[jj].w;
        }
    }
#pragma unroll
    for (int ii = 0; ii < 4; ii++) {
        const int n = n0 + ty + 16 * ii;
#pragma unroll
        for (int jj = 0; jj < 4; jj++) {
            const int oc = o0 + tx + 16 * jj;
            out[(size_t)n * EE + oc] = acc[ii][jj] + bo[oc];
        }
    }
}

extern "C" void kernel_launch(void* const* d_in, const int* in_sizes, int n_in,
                              void* d_out, int out_size, void* d_ws, size_t ws_size,
                              hipStream_t stream)
{
    const float* x    = (const float*)d_in[0];
    const int*   mask = (const int*)d_in[1];
    const float* Wq   = (const float*)d_in[2];
    const float* Wk   = (const float*)d_in[3];
    const float* Wv   = (const float*)d_in[4];
    const float* Er   = (const float*)d_in[5];
    const float* Wo   = (const float*)d_in[6];
    const float* bo   = (const float*)d_in[7];
    float* out = (float*)d_out;

    float* ws    = (float*)d_ws;
    const size_t QKV = (size_t)BB * HH * TT * SS;
    float* q     = ws;
    float* k     = ws + QKV;
    float* v     = ws + 2 * QKV;
    float* attn  = ws + 3 * QKV;
    float* vmean = ws + 4 * QKV;

    qkv_kernel<<<dim3(BB * TT), 256, 0, stream>>>(x, Wq, Wk, Wv, q, k, v);
    vmean_kernel<<<dim3(BB * HH), 256, 0, stream>>>(v, vmean);
    attn_kernel<<<dim3(TT / TR, BB * HH), 256, 0, stream>>>(q, k, v, Er, mask, vmean, attn);
    outproj_kernel<<<dim3(EE / 64, BB * TT / 64), 256, 0, stream>>>(attn, Wo, bo, out);
}

// Round 8
// 632.871 us; speedup vs baseline: 2.4824x; 2.4824x over previous
//
#include <hip/hip_runtime.h>
#include <hip/hip_bf16.h>
#include <math.h>
#include <stdint.h>

#define BB 4
#define TT 1024
#define EE 1024
#define HH 16
#define SS 64
#define NEGV -1000000000.0f

typedef unsigned short ushort_t;
typedef __attribute__((ext_vector_type(8))) short bf16x8;
typedef __attribute__((ext_vector_type(8))) unsigned short u16x8;
typedef __attribute__((ext_vector_type(4))) float f32x4;

__device__ __forceinline__ float b2f(ushort_t u) {
    union { float f; uint32_t i; } c;
    c.i = ((uint32_t)u) << 16;
    return c.f;
}
__device__ __forceinline__ ushort_t f2b(float f) {
    __hip_bfloat16 h = __float2bfloat16(f);
    return *(ushort_t*)&h;
}

// ---------------------------------------------------------------------------
// Kernel 0: Er fp32 -> bf16
// ---------------------------------------------------------------------------
__global__ __launch_bounds__(256) void ercvt_kernel(
    const float* __restrict__ Er, ushort_t* __restrict__ er16)
{
    const int i = blockIdx.x * 256 + threadIdx.x;   // 1M elements, grid 4096
    if (i < HH * TT * SS) er16[i] = f2b(Er[i]);
}

// ---------------------------------------------------------------------------
// Kernel 1: q/k/v projection -> bf16.  k pre-scaled by 1/32 (= 1/scale^2).
// ---------------------------------------------------------------------------
__global__ __launch_bounds__(256) void qkv_kernel(
    const float* __restrict__ x, const float* __restrict__ Wq,
    const float* __restrict__ Wk, const float* __restrict__ Wv,
    ushort_t* __restrict__ q, ushort_t* __restrict__ k, ushort_t* __restrict__ v)
{
    __shared__ __align__(16) float xs[EE];
    __shared__ __align__(16) float Wl[3][SS][68];
    const int bt  = blockIdx.x;
    const int bb  = bt >> 10;
    const int tt  = bt & 1023;
    const int tid = threadIdx.x;

    const float* xrow = x + (size_t)bt * EE;
    for (int i = tid; i < EE; i += 256) xs[i] = xrow[i];
    for (int i = tid; i < 3 * SS * SS; i += 256) {
        int m = i >> 12;
        int r = (i >> 6) & 63;
        int c = i & 63;
        const float* W = (m == 0) ? Wq : (m == 1) ? Wk : Wv;
        Wl[m][r][c] = W[r * 64 + c];
    }
    __syncthreads();

    const int o = tid & 63;
    const int g = tid >> 6;
    float acc[3][4];
#pragma unroll
    for (int m = 0; m < 3; m++)
#pragma unroll
        for (int t4 = 0; t4 < 4; t4++) acc[m][t4] = 0.f;

    const float4* xs4 = (const float4*)xs;
#pragma unroll
    for (int d4 = 0; d4 < 16; d4++) {
        float4 w[3];
#pragma unroll
        for (int m = 0; m < 3; m++) w[m] = *(const float4*)&Wl[m][o][d4 * 4];
#pragma unroll
        for (int t4 = 0; t4 < 4; t4++) {
            const int hh = g + 4 * t4;
            const float4 xv = xs4[hh * 16 + d4];
#pragma unroll
            for (int m = 0; m < 3; m++)
                acc[m][t4] += xv.x * w[m].x + xv.y * w[m].y + xv.z * w[m].z + xv.w * w[m].w;
        }
    }
#pragma unroll
    for (int m = 0; m < 3; m++) {
        ushort_t* dst = (m == 0) ? q : (m == 1) ? k : v;
        const float sc = (m == 1) ? 0.03125f : 1.0f;
#pragma unroll
        for (int t4 = 0; t4 < 4; t4++) {
            const int hh = g + 4 * t4;
            dst[(((size_t)bb * HH + hh) * TT + tt) * SS + o] = f2b(acc[m][t4] * sc);
        }
    }
}

// ---------------------------------------------------------------------------
// Kernel 2: vmean[b,h,d] from bf16 v
// ---------------------------------------------------------------------------
__global__ __launch_bounds__(256) void vmean_kernel(
    const ushort_t* __restrict__ v, float* __restrict__ vmean)
{
    const int bh  = blockIdx.x;
    const int tid = threadIdx.x;
    const int d   = tid & 63;
    const int jg  = tid >> 6;
    const ushort_t* vb = v + (size_t)bh * TT * SS;
    float p = 0.f;
    for (int j = jg; j < TT; j += 4) p += b2f(vb[j * SS + d]);
    __shared__ float red[4][64];
    red[jg][d] = p;
    __syncthreads();
    if (jg == 0)
        vmean[bh * SS + d] = (red[0][d] + red[1][d] + red[2][d] + red[3][d]) * (1.0f / TT);
}

// ---------------------------------------------------------------------------
// Kernel 3: MFMA bf16 flash attention with relative positions.
// scores[i,j] = q.k_scaled + q.Er[1023-(i-j)] (j<=i).  Er via band GEMM:
// per wave R = Q_w @ Es_w^T, S2[r][c] = R[r][15-r+c] (LDS gather).
// Epilogue writes the reference's scrambled layout:
//   M[b, 64h + (t>>4), 64*(t&15) + s]
// ---------------------------------------------------------------------------
__global__ __launch_bounds__(256) void attn_kernel(
    const ushort_t* __restrict__ q, const ushort_t* __restrict__ k,
    const ushort_t* __restrict__ v, const ushort_t* __restrict__ er,
    const int* __restrict__ mask, const float* __restrict__ vmean,
    float* __restrict__ attn)
{
    __shared__ __align__(16) ushort_t Qs[64][72];
    __shared__ __align__(16) ushort_t Ks[32][72];
    __shared__ __align__(16) ushort_t Vt[64][40];   // [d][j]
    __shared__ __align__(16) ushort_t Es[96][72];
    __shared__ __align__(16) float    Rs[4][16][50];
    __shared__ __align__(16) ushort_t Ps[4][16][40];

    const int tid  = threadIdx.x;
    const int lane = tid & 63;
    const int w    = tid >> 6;       // wave 0..3
    const int m    = lane & 15;
    const int qd   = lane >> 4;      // quad 0..3
    const int bh   = blockIdx.y;
    const int bb   = bh >> 4;
    const int hh   = bh & 15;
    const int i0   = blockIdx.x * 64;

    const ushort_t* qb = q + (size_t)bh * TT * SS;
    const ushort_t* kb = k + (size_t)bh * TT * SS;
    const ushort_t* vb = v + (size_t)bh * TT * SS;
    const ushort_t* eb = er + (size_t)hh * TT * SS;

    // stage Q block (64x64) once
    for (int c = tid; c < 512; c += 256) {
        int row = c >> 3, sub = c & 7;
        *(uint4*)&Qs[row][sub * 8] = ((const uint4*)qb)[(size_t)(i0 + row) * 8 + sub];
    }
    __syncthreads();

    // Q A-frags (2 K-steps), persistent across j-loop
    bf16x8 aq[2];
#pragma unroll
    for (int ks = 0; ks < 2; ks++)
        aq[ks] = *(const bf16x8*)&Qs[16 * w + m][ks * 32 + qd * 8];

    f32x4 o[4];
#pragma unroll
    for (int vt = 0; vt < 4; vt++) o[vt] = {0.f, 0.f, 0.f, 0.f};
    float mrow[4] = {-1e30f, -1e30f, -1e30f, -1e30f};
    float lrow[4] = {0.f, 0.f, 0.f, 0.f};

    const int ow = 48 - 16 * w;

    for (int j0 = 0; j0 <= i0 + 32; j0 += 32) {
        __syncthreads();
        // stage K tile (32x64)
        {
            int row = tid >> 3, sub = tid & 7;
            *(uint4*)&Ks[row][sub * 8] = ((const uint4*)kb)[(size_t)(j0 + row) * 8 + sub];
        }
        // stage V transposed: Vt[d][j]
        {
            int d = tid & 63, jh = tid >> 6;
            u16x8 tv;
#pragma unroll
            for (int jj = 0; jj < 8; jj++)
                tv[jj] = vb[(size_t)(j0 + jh * 8 + jj) * SS + d];
            *(u16x8*)&Vt[d][jh * 8] = tv;
        }
        // stage Er band (96 rows), lbase = 960 - i0 + j0, zero-fill l > 1023
        {
            const int lbase = 960 - i0 + j0;
            for (int c = tid; c < 768; c += 256) {
                int row = c >> 3, sub = c & 7;
                int l = lbase + row;
                uint4 val = {0u, 0u, 0u, 0u};
                if (l <= 1023) val = ((const uint4*)eb)[(size_t)l * 8 + sub];
                *(uint4*)&Es[row][sub * 8] = val;
            }
        }
        __syncthreads();

        // S = Q @ K^T  (2 col-tiles)
        f32x4 s[2];
#pragma unroll
        for (int ct = 0; ct < 2; ct++) {
            s[ct] = {0.f, 0.f, 0.f, 0.f};
#pragma unroll
            for (int ks = 0; ks < 2; ks++) {
                bf16x8 bk = *(const bf16x8*)&Ks[16 * ct + m][ks * 32 + qd * 8];
                s[ct] = __builtin_amdgcn_mfma_f32_16x16x32_bf16(aq[ks], bk, s[ct], 0, 0, 0);
            }
        }
        // R = Q @ Es_w^T  (3 col-tiles), write to per-wave scratch
#pragma unroll
        for (int rt = 0; rt < 3; rt++) {
            f32x4 r = {0.f, 0.f, 0.f, 0.f};
#pragma unroll
            for (int ks = 0; ks < 2; ks++) {
                bf16x8 be = *(const bf16x8*)&Es[ow + 16 * rt + m][ks * 32 + qd * 8];
                r = __builtin_amdgcn_mfma_f32_16x16x32_bf16(aq[ks], be, r, 0, 0, 0);
            }
#pragma unroll
            for (int reg = 0; reg < 4; reg++)
                Rs[w][qd * 4 + reg][16 * rt + m] = r[reg];
        }

        // gather skew band + causal mask
        float sv[2][4];
#pragma unroll
        for (int ct = 0; ct < 2; ct++)
#pragma unroll
            for (int reg = 0; reg < 4; reg++) {
                const int r_ = qd * 4 + reg;
                const int c_ = m + 16 * ct;
                const int i_ = i0 + 16 * w + r_;
                const int j_ = j0 + c_;
                float val = s[ct][reg] + Rs[w][r_][15 - r_ + c_];
                sv[ct][reg] = (j_ > i_) ? NEGV : val;
            }

        // online softmax (each quad owns rows 4qd..4qd+3)
        float alpha[4];
#pragma unroll
        for (int reg = 0; reg < 4; reg++) {
            float mx = fmaxf(sv[0][reg], sv[1][reg]);
#pragma unroll
            for (int off = 1; off < 16; off <<= 1)
                mx = fmaxf(mx, __shfl_xor(mx, off));
            const float nm = fmaxf(mrow[reg], mx);
            const float al = __expf(mrow[reg] - nm);
            const float p0 = __expf(sv[0][reg] - nm);
            const float p1 = __expf(sv[1][reg] - nm);
            float ps = p0 + p1;
#pragma unroll
            for (int off = 1; off < 16; off <<= 1)
                ps += __shfl_xor(ps, off);
            lrow[reg] = lrow[reg] * al + ps;
            mrow[reg] = nm;
            alpha[reg] = al;
            Ps[w][qd * 4 + reg][m]      = f2b(p0);
            Ps[w][qd * 4 + reg][m + 16] = f2b(p1);
        }

        // rescale O, then O += P @ V
#pragma unroll
        for (int vt = 0; vt < 4; vt++)
#pragma unroll
            for (int reg = 0; reg < 4; reg++) o[vt][reg] *= alpha[reg];

        bf16x8 pa = *(const bf16x8*)&Ps[w][m][qd * 8];
#pragma unroll
        for (int vt = 0; vt < 4; vt++) {
            bf16x8 bv = *(const bf16x8*)&Vt[16 * vt + m][qd * 8];
            o[vt] = __builtin_amdgcn_mfma_f32_16x16x32_bf16(pa, bv, o[vt], 0, 0, 0);
        }
    }

    // epilogue: /l, padded-row override, scrambled store
#pragma unroll
    for (int reg = 0; reg < 4; reg++) {
        const int r_ = qd * 4 + reg;
        const int i_ = i0 + 16 * w + r_;
        const bool pad = (mask[bb * TT + i_] == 0);
        const float inv = 1.0f / lrow[reg];
        const size_t rowbase = ((size_t)bb * TT + hh * 64 + (i_ >> 4)) * EE + (i_ & 15) * 64;
#pragma unroll
        for (int vt = 0; vt < 4; vt++) {
            const int d_ = 16 * vt + m;
            float val = pad ? vmean[bh * SS + d_] : o[vt][reg] * inv;
            attn[rowbase + d_] = val;
        }
    }
}

// ---------------------------------------------------------------------------
// Kernel 4: out = M @ Wo^T + bo   (fp32, unchanged)
// ---------------------------------------------------------------------------
__global__ __launch_bounds__(256) void outproj_kernel(
    const float* __restrict__ A, const float* __restrict__ Wo,
    const float* __restrict__ bo, float* __restrict__ out)
{
    __shared__ __align__(16) float As[64][36];
    __shared__ __align__(16) float Ws[64][36];
    const int tid = threadIdx.x;
    const int o0  = blockIdx.x * 64;
    const int n0  = blockIdx.y * 64;
    const int tx  = tid & 15;
    const int ty  = tid >> 4;

    float acc[4][4];
#pragma unroll
    for (int ii = 0; ii < 4; ii++)
#pragma unroll
        for (int jj = 0; jj < 4; jj++) acc[ii][jj] = 0.f;

    for (int k0 = 0; k0 < 1024; k0 += 32) {
        __syncthreads();
        for (int idx = tid; idx < 2048; idx += 256) {
            int r = idx >> 5, kk = idx & 31;
            As[r][kk] = A[(size_t)(n0 + r) * 1024 + k0 + kk];
            Ws[r][kk] = Wo[(size_t)(o0 + r) * 1024 + k0 + kk];
        }
        __syncthreads();
#pragma unroll
        for (int k4 = 0; k4 < 8; k4++) {
            float4 av[4], wv[4];
#pragma unroll
            for (int ii = 0; ii < 4; ii++) av[ii] = *(const float4*)&As[ty + 16 * ii][k4 * 4];
#pragma unroll
            for (int jj = 0; jj < 4; jj++) wv[jj] = *(const float4*)&Ws[tx + 16 * jj][k4 * 4];
#pragma unroll
            for (int ii = 0; ii < 4; ii++)
#pragma unroll
                for (int jj = 0; jj < 4; jj++)
                    acc[ii][jj] += av[ii].x * wv[jj].x + av[ii].y * wv[jj].y
                                 + av[ii].z * wv[jj].z + av[ii].w * wv[jj].w;
        }
    }
#pragma unroll
    for (int ii = 0; ii < 4; ii++) {
        const int n = n0 + ty + 16 * ii;
#pragma unroll
        for (int jj = 0; jj < 4; jj++) {
            const int oc = o0 + tx + 16 * jj;
            out[(size_t)n * EE + oc] = acc[ii][jj] + bo[oc];
        }
    }
}

// ---------------------------------------------------------------------------
// Launcher.  ws layout: q16|k16|v16 (8MB each) | er16 (2MB) | attn f32 (16MB)
//            | vmean (16KB)
// ---------------------------------------------------------------------------
extern "C" void kernel_launch(void* const* d_in, const int* in_sizes, int n_in,
                              void* d_out, int out_size, void* d_ws, size_t ws_size,
                              hipStream_t stream)
{
    const float* x    = (const float*)d_in[0];
    const int*   mask = (const int*)d_in[1];
    const float* Wq   = (const float*)d_in[2];
    const float* Wk   = (const float*)d_in[3];
    const float* Wv   = (const float*)d_in[4];
    const float* Er   = (const float*)d_in[5];
    const float* Wo   = (const float*)d_in[6];
    const float* bo   = (const float*)d_in[7];
    float* out = (float*)d_out;

    const size_t QKV = (size_t)BB * HH * TT * SS;   // 4194304
    ushort_t* q16  = (ushort_t*)d_ws;
    ushort_t* k16  = q16 + QKV;
    ushort_t* v16  = k16 + QKV;
    ushort_t* er16 = v16 + QKV;                      // 1048576
    float* attn    = (float*)(er16 + (size_t)HH * TT * SS);
    float* vmean   = attn + QKV;

    ercvt_kernel<<<dim3(4096), 256, 0, stream>>>(Er, er16);
    qkv_kernel<<<dim3(BB * TT), 256, 0, stream>>>(x, Wq, Wk, Wv, q16, k16, v16);
    vmean_kernel<<<dim3(BB * HH), 256, 0, stream>>>(v16, vmean);
    attn_kernel<<<dim3(16, BB * HH), 256, 0, stream>>>(q16, k16, v16, er16, mask, vmean, attn);
    outproj_kernel<<<dim3(EE / 64, BB * TT / 64), 256, 0, stream>>>(attn, Wo, bo, out);
}

// Round 9
// 384.315 us; speedup vs baseline: 4.0879x; 1.6467x over previous
//
#include <hip/hip_runtime.h>
#include <hip/hip_bf16.h>
#include <math.h>
#include <stdint.h>

#define BB 4
#define TT 1024
#define EE 1024
#define HH 16
#define SS 64
#define NEGV -1000000000.0f

typedef unsigned short ushort_t;
typedef __attribute__((ext_vector_type(8))) short bf16x8;
typedef __attribute__((ext_vector_type(8))) unsigned short u16x8;
typedef __attribute__((ext_vector_type(4))) float f32x4;

__device__ __forceinline__ float b2f(ushort_t u) {
    union { float f; uint32_t i; } c;
    c.i = ((uint32_t)u) << 16;
    return c.f;
}
__device__ __forceinline__ ushort_t f2b(float f) {
    __hip_bfloat16 h = __float2bfloat16(f);
    return *(ushort_t*)&h;
}

// ---------------------------------------------------------------------------
// Kernel 0: fp32 -> bf16 converter (used for Er and Wo)
// ---------------------------------------------------------------------------
__global__ __launch_bounds__(256) void cvt_kernel(
    const float* __restrict__ src, ushort_t* __restrict__ dst, int n)
{
    const int i = blockIdx.x * 256 + threadIdx.x;
    if (i < n) dst[i] = f2b(src[i]);
}

// ---------------------------------------------------------------------------
// Kernel 1: q/k/v projection -> bf16.  k pre-scaled by 1/32 (= 1/scale^2).
// ---------------------------------------------------------------------------
__global__ __launch_bounds__(256) void qkv_kernel(
    const float* __restrict__ x, const float* __restrict__ Wq,
    const float* __restrict__ Wk, const float* __restrict__ Wv,
    ushort_t* __restrict__ q, ushort_t* __restrict__ k, ushort_t* __restrict__ v)
{
    __shared__ __align__(16) float xs[EE];
    __shared__ __align__(16) float Wl[3][SS][68];
    const int bt  = blockIdx.x;
    const int bb  = bt >> 10;
    const int tt  = bt & 1023;
    const int tid = threadIdx.x;

    const float* xrow = x + (size_t)bt * EE;
    for (int i = tid; i < EE; i += 256) xs[i] = xrow[i];
    for (int i = tid; i < 3 * SS * SS; i += 256) {
        int m = i >> 12;
        int r = (i >> 6) & 63;
        int c = i & 63;
        const float* W = (m == 0) ? Wq : (m == 1) ? Wk : Wv;
        Wl[m][r][c] = W[r * 64 + c];
    }
    __syncthreads();

    const int o = tid & 63;
    const int g = tid >> 6;
    float acc[3][4];
#pragma unroll
    for (int m = 0; m < 3; m++)
#pragma unroll
        for (int t4 = 0; t4 < 4; t4++) acc[m][t4] = 0.f;

    const float4* xs4 = (const float4*)xs;
#pragma unroll
    for (int d4 = 0; d4 < 16; d4++) {
        float4 w[3];
#pragma unroll
        for (int m = 0; m < 3; m++) w[m] = *(const float4*)&Wl[m][o][d4 * 4];
#pragma unroll
        for (int t4 = 0; t4 < 4; t4++) {
            const int hh = g + 4 * t4;
            const float4 xv = xs4[hh * 16 + d4];
#pragma unroll
            for (int m = 0; m < 3; m++)
                acc[m][t4] += xv.x * w[m].x + xv.y * w[m].y + xv.z * w[m].z + xv.w * w[m].w;
        }
    }
#pragma unroll
    for (int m = 0; m < 3; m++) {
        ushort_t* dst = (m == 0) ? q : (m == 1) ? k : v;
        const float sc = (m == 1) ? 0.03125f : 1.0f;
#pragma unroll
        for (int t4 = 0; t4 < 4; t4++) {
            const int hh = g + 4 * t4;
            dst[(((size_t)bb * HH + hh) * TT + tt) * SS + o] = f2b(acc[m][t4] * sc);
        }
    }
}

// ---------------------------------------------------------------------------
// Kernel 2: vmean[b,h,d] from bf16 v
// ---------------------------------------------------------------------------
__global__ __launch_bounds__(256) void vmean_kernel(
    const ushort_t* __restrict__ v, float* __restrict__ vmean)
{
    const int bh  = blockIdx.x;
    const int tid = threadIdx.x;
    const int d   = tid & 63;
    const int jg  = tid >> 6;
    const ushort_t* vb = v + (size_t)bh * TT * SS;
    float p = 0.f;
    for (int j = jg; j < TT; j += 4) p += b2f(vb[j * SS + d]);
    __shared__ float red[4][64];
    red[jg][d] = p;
    __syncthreads();
    if (jg == 0)
        vmean[bh * SS + d] = (red[0][d] + red[1][d] + red[2][d] + red[3][d]) * (1.0f / TT);
}

// ---------------------------------------------------------------------------
// Kernel 3: MFMA bf16 flash attention (verified R8 logic).
// Epilogue writes the scrambled pre-projection matrix in BF16:
//   M[b, 64h + (t>>4), 64*(t&15) + s]
// ---------------------------------------------------------------------------
__global__ __launch_bounds__(256) void attn_kernel(
    const ushort_t* __restrict__ q, const ushort_t* __restrict__ k,
    const ushort_t* __restrict__ v, const ushort_t* __restrict__ er,
    const int* __restrict__ mask, const float* __restrict__ vmean,
    ushort_t* __restrict__ attn)
{
    __shared__ __align__(16) ushort_t Qs[64][72];
    __shared__ __align__(16) ushort_t Ks[32][72];
    __shared__ __align__(16) ushort_t Vt[64][40];   // [d][j]
    __shared__ __align__(16) ushort_t Es[96][72];
    __shared__ __align__(16) float    Rs[4][16][50];
    __shared__ __align__(16) ushort_t Ps[4][16][40];

    const int tid  = threadIdx.x;
    const int lane = tid & 63;
    const int w    = tid >> 6;       // wave 0..3
    const int m    = lane & 15;
    const int qd   = lane >> 4;      // quad 0..3
    const int bh   = blockIdx.y;
    const int bb   = bh >> 4;
    const int hh   = bh & 15;
    const int i0   = blockIdx.x * 64;

    const ushort_t* qb = q + (size_t)bh * TT * SS;
    const ushort_t* kb = k + (size_t)bh * TT * SS;
    const ushort_t* vb = v + (size_t)bh * TT * SS;
    const ushort_t* eb = er + (size_t)hh * TT * SS;

    for (int c = tid; c < 512; c += 256) {
        int row = c >> 3, sub = c & 7;
        *(uint4*)&Qs[row][sub * 8] = ((const uint4*)qb)[(size_t)(i0 + row) * 8 + sub];
    }
    __syncthreads();

    bf16x8 aq[2];
#pragma unroll
    for (int ks = 0; ks < 2; ks++)
        aq[ks] = *(const bf16x8*)&Qs[16 * w + m][ks * 32 + qd * 8];

    f32x4 o[4];
#pragma unroll
    for (int vt = 0; vt < 4; vt++) o[vt] = {0.f, 0.f, 0.f, 0.f};
    float mrow[4] = {-1e30f, -1e30f, -1e30f, -1e30f};
    float lrow[4] = {0.f, 0.f, 0.f, 0.f};

    const int ow = 48 - 16 * w;

    for (int j0 = 0; j0 <= i0 + 32; j0 += 32) {
        __syncthreads();
        {
            int row = tid >> 3, sub = tid & 7;
            *(uint4*)&Ks[row][sub * 8] = ((const uint4*)kb)[(size_t)(j0 + row) * 8 + sub];
        }
        {
            int d = tid & 63, jh = tid >> 6;
            u16x8 tv;
#pragma unroll
            for (int jj = 0; jj < 8; jj++)
                tv[jj] = vb[(size_t)(j0 + jh * 8 + jj) * SS + d];
            *(u16x8*)&Vt[d][jh * 8] = tv;
        }
        {
            const int lbase = 960 - i0 + j0;
            for (int c = tid; c < 768; c += 256) {
                int row = c >> 3, sub = c & 7;
                int l = lbase + row;
                uint4 val = {0u, 0u, 0u, 0u};
                if (l <= 1023) val = ((const uint4*)eb)[(size_t)l * 8 + sub];
                *(uint4*)&Es[row][sub * 8] = val;
            }
        }
        __syncthreads();

        f32x4 s[2];
#pragma unroll
        for (int ct = 0; ct < 2; ct++) {
            s[ct] = {0.f, 0.f, 0.f, 0.f};
#pragma unroll
            for (int ks = 0; ks < 2; ks++) {
                bf16x8 bk = *(const bf16x8*)&Ks[16 * ct + m][ks * 32 + qd * 8];
                s[ct] = __builtin_amdgcn_mfma_f32_16x16x32_bf16(aq[ks], bk, s[ct], 0, 0, 0);
            }
        }
#pragma unroll
        for (int rt = 0; rt < 3; rt++) {
            f32x4 r = {0.f, 0.f, 0.f, 0.f};
#pragma unroll
            for (int ks = 0; ks < 2; ks++) {
                bf16x8 be = *(const bf16x8*)&Es[ow + 16 * rt + m][ks * 32 + qd * 8];
                r = __builtin_amdgcn_mfma_f32_16x16x32_bf16(aq[ks], be, r, 0, 0, 0);
            }
#pragma unroll
            for (int reg = 0; reg < 4; reg++)
                Rs[w][qd * 4 + reg][16 * rt + m] = r[reg];
        }

        float sv[2][4];
#pragma unroll
        for (int ct = 0; ct < 2; ct++)
#pragma unroll
            for (int reg = 0; reg < 4; reg++) {
                const int r_ = qd * 4 + reg;
                const int c_ = m + 16 * ct;
                const int i_ = i0 + 16 * w + r_;
                const int j_ = j0 + c_;
                float val = s[ct][reg] + Rs[w][r_][15 - r_ + c_];
                sv[ct][reg] = (j_ > i_) ? NEGV : val;
            }

        float alpha[4];
#pragma unroll
        for (int reg = 0; reg < 4; reg++) {
            float mx = fmaxf(sv[0][reg], sv[1][reg]);
#pragma unroll
            for (int off = 1; off < 16; off <<= 1)
                mx = fmaxf(mx, __shfl_xor(mx, off));
            const float nm = fmaxf(mrow[reg], mx);
            const float al = __expf(mrow[reg] - nm);
            const float p0 = __expf(sv[0][reg] - nm);
            const float p1 = __expf(sv[1][reg] - nm);
            float ps = p0 + p1;
#pragma unroll
            for (int off = 1; off < 16; off <<= 1)
                ps += __shfl_xor(ps, off);
            lrow[reg] = lrow[reg] * al + ps;
            mrow[reg] = nm;
            alpha[reg] = al;
            Ps[w][qd * 4 + reg][m]      = f2b(p0);
            Ps[w][qd * 4 + reg][m + 16] = f2b(p1);
        }

#pragma unroll
        for (int vt = 0; vt < 4; vt++)
#pragma unroll
            for (int reg = 0; reg < 4; reg++) o[vt][reg] *= alpha[reg];

        bf16x8 pa = *(const bf16x8*)&Ps[w][m][qd * 8];
#pragma unroll
        for (int vt = 0; vt < 4; vt++) {
            bf16x8 bv = *(const bf16x8*)&Vt[16 * vt + m][qd * 8];
            o[vt] = __builtin_amdgcn_mfma_f32_16x16x32_bf16(pa, bv, o[vt], 0, 0, 0);
        }
    }

    // epilogue: /l, padded-row override, scrambled BF16 store
#pragma unroll
    for (int reg = 0; reg < 4; reg++) {
        const int r_ = qd * 4 + reg;
        const int i_ = i0 + 16 * w + r_;
        const bool pad = (mask[bb * TT + i_] == 0);
        const float inv = 1.0f / lrow[reg];
        const size_t rowbase = ((size_t)bb * TT + hh * 64 + (i_ >> 4)) * EE + (i_ & 15) * 64;
#pragma unroll
        for (int vt = 0; vt < 4; vt++) {
            const int d_ = 16 * vt + m;
            float val = pad ? vmean[bh * SS + d_] : o[vt][reg] * inv;
            attn[rowbase + d_] = f2b(val);
        }
    }
}

// ---------------------------------------------------------------------------
// Kernel 4: MFMA bf16 GEMM  out = M @ Wo16^T + bo.
// M (4096x1024 bf16, scrambled rows), Wo16 (1024x1024 bf16), out fp32.
// 128x128 tile, BK=32; 4 waves each own a 64x64 quadrant (4x4 of 16x16x32).
// LDS [128][36] bf16: +4 pad -> frag-read start banks 18m+4qd (distinct even)
// -> only free 2-way overlaps.
// ---------------------------------------------------------------------------
__global__ __launch_bounds__(256) void outproj_kernel(
    const ushort_t* __restrict__ A, const ushort_t* __restrict__ Wo,
    const float* __restrict__ bo, float* __restrict__ out)
{
    __shared__ __align__(16) ushort_t As[128][36];
    __shared__ __align__(16) ushort_t Bs[128][36];

    const int tid  = threadIdx.x;
    const int lane = tid & 63;
    const int w    = tid >> 6;
    const int m    = lane & 15;
    const int qd   = lane >> 4;
    const int wrow = (w & 1) * 64;
    const int wcol = (w >> 1) * 64;
    const int o0   = blockIdx.x * 128;
    const int n0   = blockIdx.y * 128;

    f32x4 acc[4][4];
#pragma unroll
    for (int rt = 0; rt < 4; rt++)
#pragma unroll
        for (int ct = 0; ct < 4; ct++) acc[rt][ct] = {0.f, 0.f, 0.f, 0.f};

    for (int k0 = 0; k0 < 1024; k0 += 32) {
        __syncthreads();
#pragma unroll
        for (int l = 0; l < 2; l++) {
            const int idx = tid + 256 * l;          // 0..511
            const int row = idx >> 2;
            const int sub = idx & 3;
            *(uint4*)&As[row][sub * 8] =
                *(const uint4*)&A[(size_t)(n0 + row) * 1024 + k0 + sub * 8];
            *(uint4*)&Bs[row][sub * 8] =
                *(const uint4*)&Wo[(size_t)(o0 + row) * 1024 + k0 + sub * 8];
        }
        __syncthreads();

        bf16x8 af[4], bf[4];
#pragma unroll
        for (int rt = 0; rt < 4; rt++)
            af[rt] = *(const bf16x8*)&As[wrow + rt * 16 + m][qd * 8];
#pragma unroll
        for (int ct = 0; ct < 4; ct++)
            bf[ct] = *(const bf16x8*)&Bs[wcol + ct * 16 + m][qd * 8];
#pragma unroll
        for (int rt = 0; rt < 4; rt++)
#pragma unroll
            for (int ct = 0; ct < 4; ct++)
                acc[rt][ct] = __builtin_amdgcn_mfma_f32_16x16x32_bf16(
                    af[rt], bf[ct], acc[rt][ct], 0, 0, 0);
    }

#pragma unroll
    for (int rt = 0; rt < 4; rt++) {
#pragma unroll
        for (int ct = 0; ct < 4; ct++) {
            const int oc = o0 + wcol + ct * 16 + m;
            const float bias = bo[oc];
#pragma unroll
            for (int reg = 0; reg < 4; reg++) {
                const int n = n0 + wrow + rt * 16 + qd * 4 + reg;
                out[(size_t)n * EE + oc] = acc[rt][ct][reg] + bias;
            }
        }
    }
}

// ---------------------------------------------------------------------------
// Launcher.  ws layout (ushort): q16|k16|v16 (4M each) | er16 (1M) | wo16 (1M)
//            | M16 (4M) | vmean f32 (4096)
// ---------------------------------------------------------------------------
extern "C" void kernel_launch(void* const* d_in, const int* in_sizes, int n_in,
                              void* d_out, int out_size, void* d_ws, size_t ws_size,
                              hipStream_t stream)
{
    const float* x    = (const float*)d_in[0];
    const int*   mask = (const int*)d_in[1];
    const float* Wq   = (const float*)d_in[2];
    const float* Wk   = (const float*)d_in[3];
    const float* Wv   = (const float*)d_in[4];
    const float* Er   = (const float*)d_in[5];
    const float* Wo   = (const float*)d_in[6];
    const float* bo   = (const float*)d_in[7];
    float* out = (float*)d_out;

    const size_t QKV = (size_t)BB * HH * TT * SS;   // 4194304
    const int    nEr = HH * TT * SS;                // 1048576
    const int    nWo = EE * EE;                     // 1048576
    ushort_t* q16  = (ushort_t*)d_ws;
    ushort_t* k16  = q16 + QKV;
    ushort_t* v16  = k16 + QKV;
    ushort_t* er16 = v16 + QKV;
    ushort_t* wo16 = er16 + nEr;
    ushort_t* M16  = wo16 + nWo;
    float*    vmean = (float*)(M16 + QKV);

    cvt_kernel<<<dim3(4096), 256, 0, stream>>>(Er, er16, nEr);
    cvt_kernel<<<dim3(4096), 256, 0, stream>>>(Wo, wo16, nWo);
    qkv_kernel<<<dim3(BB * TT), 256, 0, stream>>>(x, Wq, Wk, Wv, q16, k16, v16);
    vmean_kernel<<<dim3(BB * HH), 256, 0, stream>>>(v16, vmean);
    attn_kernel<<<dim3(16, BB * HH), 256, 0, stream>>>(q16, k16, v16, er16, mask, vmean, M16);
    outproj_kernel<<<dim3(EE / 128, BB * TT / 128), 256, 0, stream>>>(M16, wo16, bo, out);
}

// Round 10
// 291.305 us; speedup vs baseline: 5.3931x; 1.3193x over previous
//
#include <hip/hip_runtime.h>
#include <hip/hip_bf16.h>
#include <math.h>
#include <stdint.h>

#define BB 4
#define TT 1024
#define EE 1024
#define HH 16
#define SS 64

typedef unsigned short ushort_t;
typedef __attribute__((ext_vector_type(8))) short bf16x8;
typedef __attribute__((ext_vector_type(8))) unsigned short u16x8;
typedef __attribute__((ext_vector_type(4))) unsigned short u16x4;
typedef __attribute__((ext_vector_type(4))) float f32x4;

__device__ __forceinline__ float b2f(ushort_t u) {
    union { float f; uint32_t i; } c;
    c.i = ((uint32_t)u) << 16;
    return c.f;
}
__device__ __forceinline__ ushort_t f2b(float f) {
    __hip_bfloat16 h = __float2bfloat16(f);
    return *(ushort_t*)&h;
}

// ---------------------------------------------------------------------------
// Kernel 0: fp32 -> bf16 converter (Er, Wo)
// ---------------------------------------------------------------------------
__global__ __launch_bounds__(256) void cvt_kernel(
    const float* __restrict__ src, ushort_t* __restrict__ dst, int n)
{
    const int i = blockIdx.x * 256 + threadIdx.x;
    if (i < n) dst[i] = f2b(src[i]);
}

// ---------------------------------------------------------------------------
// Kernel 1: MFMA q/k/v projection.  Block = (128 t-rows, one head).
// q[b,h,t,o] = sum_i x[b,t,64h+i] * W[o,i]; k scaled by 1/32.
// K=64 -> 2 MFMA steps, no k-loop.  Inline fp32->bf16 staging.
// ---------------------------------------------------------------------------
__global__ __launch_bounds__(256) void qkv_kernel(
    const float* __restrict__ x, const float* __restrict__ Wq,
    const float* __restrict__ Wk, const float* __restrict__ Wv,
    ushort_t* __restrict__ q, ushort_t* __restrict__ k, ushort_t* __restrict__ v)
{
    __shared__ __align__(16) ushort_t Xs[128][72];
    __shared__ __align__(16) ushort_t Wl[3][64][72];

    const int tid  = threadIdx.x;
    const int lane = tid & 63;
    const int w    = tid >> 6;
    const int m    = lane & 15;
    const int qd   = lane >> 4;
    const int n0   = blockIdx.x * 128;        // global row (b*1024+t)
    const int hh   = blockIdx.y;
    const int bb   = n0 >> 10;                // uniform (128 | 1024)

    // stage x slice (128 x 64) fp32 -> bf16
#pragma unroll
    for (int l = 0; l < 8; l++) {
        const int idx = tid + 256 * l;        // 0..2047 float4s
        const int row = idx >> 4;
        const int c4  = idx & 15;
        const float4 xv = *(const float4*)&x[(size_t)(n0 + row) * 1024 + hh * 64 + c4 * 4];
        u16x4 o4 = { f2b(xv.x), f2b(xv.y), f2b(xv.z), f2b(xv.w) };
        *(u16x4*)&Xs[row][c4 * 4] = o4;
    }
    // stage Wq/Wk/Wv (3 x 64 x 64) fp32 -> bf16
#pragma unroll
    for (int l = 0; l < 12; l++) {
        const int idx = tid + 256 * l;        // 0..3071 float4s
        const int mo  = idx >> 10;
        const int r   = (idx >> 4) & 63;
        const int c4  = idx & 15;
        const float* W = (mo == 0) ? Wq : (mo == 1) ? Wk : Wv;
        const float4 wv = *(const float4*)&W[r * 64 + c4 * 4];
        u16x4 o4 = { f2b(wv.x), f2b(wv.y), f2b(wv.z), f2b(wv.w) };
        *(u16x4*)&Wl[mo][r][c4 * 4] = o4;
    }
    __syncthreads();

    // wave w owns rows 32w..32w+31 (2 row-tiles) x 3 outputs x 4 col-tiles
    f32x4 acc[2][3][4];
#pragma unroll
    for (int rt = 0; rt < 2; rt++)
#pragma unroll
        for (int mo = 0; mo < 3; mo++)
#pragma unroll
            for (int ct = 0; ct < 4; ct++) acc[rt][mo][ct] = {0.f, 0.f, 0.f, 0.f};

#pragma unroll
    for (int ks = 0; ks < 2; ks++) {
        bf16x8 af[2];
#pragma unroll
        for (int rt = 0; rt < 2; rt++)
            af[rt] = *(const bf16x8*)&Xs[32 * w + 16 * rt + m][ks * 32 + qd * 8];
#pragma unroll
        for (int mo = 0; mo < 3; mo++)
#pragma unroll
            for (int ct = 0; ct < 4; ct++) {
                bf16x8 bw = *(const bf16x8*)&Wl[mo][ct * 16 + m][ks * 32 + qd * 8];
#pragma unroll
                for (int rt = 0; rt < 2; rt++)
                    acc[rt][mo][ct] = __builtin_amdgcn_mfma_f32_16x16x32_bf16(
                        af[rt], bw, acc[rt][mo][ct], 0, 0, 0);
            }
    }

    const size_t obase = ((size_t)bb * HH + hh) * TT;
#pragma unroll
    for (int mo = 0; mo < 3; mo++) {
        ushort_t* dst = (mo == 0) ? q : (mo == 1) ? k : v;
        const float sc = (mo == 1) ? 0.03125f : 1.0f;
#pragma unroll
        for (int rt = 0; rt < 2; rt++)
#pragma unroll
            for (int reg = 0; reg < 4; reg++) {
                const int t = (n0 & 1023) + 32 * w + 16 * rt + qd * 4 + reg;
#pragma unroll
                for (int ct = 0; ct < 4; ct++)
                    dst[(obase + t) * SS + ct * 16 + m] = f2b(acc[rt][mo][ct][reg] * sc);
            }
    }
}

// ---------------------------------------------------------------------------
// Kernel 2: vmean[b,h,d] from bf16 v
// ---------------------------------------------------------------------------
__global__ __launch_bounds__(256) void vmean_kernel(
    const ushort_t* __restrict__ v, float* __restrict__ vmean)
{
    const int bh  = blockIdx.x;
    const int tid = threadIdx.x;
    const int d   = tid & 63;
    const int jg  = tid >> 6;
    const ushort_t* vb = v + (size_t)bh * TT * SS;
    float p = 0.f;
    for (int j = jg; j < TT; j += 4) p += b2f(vb[j * SS + d]);
    __shared__ float red[4][64];
    red[jg][d] = p;
    __syncthreads();
    if (jg == 0)
        vmean[bh * SS + d] = (red[0][d] + red[1][d] + red[2][d] + red[3][d]) * (1.0f / TT);
}

// ---------------------------------------------------------------------------
// Kernel 3: MFMA bf16 flash attention, fixed-max softmax (scores bounded),
// Es ring buffer (96 rows, stage 32/iter).  Scrambled bf16 output:
//   M[b, 64h + (t>>4), 64*(t&15) + s]
// ---------------------------------------------------------------------------
__global__ __launch_bounds__(256) void attn_kernel(
    const ushort_t* __restrict__ q, const ushort_t* __restrict__ k,
    const ushort_t* __restrict__ v, const ushort_t* __restrict__ er,
    const int* __restrict__ mask, const float* __restrict__ vmean,
    ushort_t* __restrict__ attn)
{
    __shared__ __align__(16) ushort_t Qs[64][72];
    __shared__ __align__(16) ushort_t Ks[32][72];
    __shared__ __align__(16) ushort_t Vt[64][40];   // [d][j]
    __shared__ __align__(16) ushort_t Es[96][72];   // ring buffer
    __shared__ __align__(16) float    Rs[4][16][50];
    __shared__ __align__(16) ushort_t Ps[4][16][40];

    const int tid  = threadIdx.x;
    const int lane = tid & 63;
    const int w    = tid >> 6;
    const int m    = lane & 15;
    const int qd   = lane >> 4;
    const int bh   = blockIdx.y;
    const int bb   = bh >> 4;
    const int hh   = bh & 15;
    const int i0   = blockIdx.x * 64;

    const ushort_t* qb = q + (size_t)bh * TT * SS;
    const ushort_t* kb = k + (size_t)bh * TT * SS;
    const ushort_t* vb = v + (size_t)bh * TT * SS;
    const ushort_t* eb = er + (size_t)hh * TT * SS;
    const int l0 = 960 - i0;

    // stage Q (64x64) and Es ring prologue (slots 0..95 = l0..l0+95)
    for (int c = tid; c < 512; c += 256) {
        int row = c >> 3, sub = c & 7;
        *(uint4*)&Qs[row][sub * 8] = ((const uint4*)qb)[(size_t)(i0 + row) * 8 + sub];
    }
    for (int c = tid; c < 768; c += 256) {
        int row = c >> 3, sub = c & 7;
        int l = l0 + row;
        uint4 val = {0u, 0u, 0u, 0u};
        if (l <= 1023) val = ((const uint4*)eb)[(size_t)l * 8 + sub];
        *(uint4*)&Es[row][sub * 8] = val;
    }
    __syncthreads();

    bf16x8 aq[2];
#pragma unroll
    for (int ks = 0; ks < 2; ks++)
        aq[ks] = *(const bf16x8*)&Qs[16 * w + m][ks * 32 + qd * 8];

    f32x4 o[4];
#pragma unroll
    for (int vt = 0; vt < 4; vt++) o[vt] = {0.f, 0.f, 0.f, 0.f};
    float lsum[4] = {0.f, 0.f, 0.f, 0.f};

    const int ow = 48 - 16 * w;

    for (int j0 = 0; j0 <= i0 + 32; j0 += 32) {
        __syncthreads();
        {   // K tile (32x64)
            int row = tid >> 3, sub = tid & 7;
            *(uint4*)&Ks[row][sub * 8] = ((const uint4*)kb)[(size_t)(j0 + row) * 8 + sub];
        }
        {   // V transposed Vt[d][j]
            int d = tid & 63, jh = tid >> 6;
            u16x8 tv;
#pragma unroll
            for (int jj = 0; jj < 8; jj++)
                tv[jj] = vb[(size_t)(j0 + jh * 8 + jj) * SS + d];
            *(u16x8*)&Vt[d][jh * 8] = tv;
        }
        if (j0 > 0) {   // ring: stage 32 new Er rows into expired slots
            const int sb  = (j0 - 32) % 96;
            const int row = tid >> 3, sub = tid & 7;
            const int l   = l0 + 64 + j0 + row;
            uint4 val = {0u, 0u, 0u, 0u};
            if (l <= 1023) val = ((const uint4*)eb)[(size_t)l * 8 + sub];
            *(uint4*)&Es[sb + row][sub * 8] = val;
        }
        __syncthreads();

        // S = Q @ K^T
        f32x4 s[2];
#pragma unroll
        for (int ct = 0; ct < 2; ct++) {
            s[ct] = {0.f, 0.f, 0.f, 0.f};
#pragma unroll
            for (int ks = 0; ks < 2; ks++) {
                bf16x8 bk = *(const bf16x8*)&Ks[16 * ct + m][ks * 32 + qd * 8];
                s[ct] = __builtin_amdgcn_mfma_f32_16x16x32_bf16(aq[ks], bk, s[ct], 0, 0, 0);
            }
        }
        // R = Q @ Es_band^T  (ring-indexed)
#pragma unroll
        for (int rt = 0; rt < 3; rt++) {
            const int row0 = (ow + 16 * rt + j0) % 96;   // multiple of 16
            f32x4 r = {0.f, 0.f, 0.f, 0.f};
#pragma unroll
            for (int ks = 0; ks < 2; ks++) {
                bf16x8 be = *(const bf16x8*)&Es[row0 + m][ks * 32 + qd * 8];
                r = __builtin_amdgcn_mfma_f32_16x16x32_bf16(aq[ks], be, r, 0, 0, 0);
            }
#pragma unroll
            for (int reg = 0; reg < 4; reg++)
                Rs[w][qd * 4 + reg][16 * rt + m] = r[reg];
        }

        // fixed-max softmax: p = exp(s) (0 if masked); lane-local l accum
#pragma unroll
        for (int reg = 0; reg < 4; reg++) {
            const int r_ = qd * 4 + reg;
            const int i_ = i0 + 16 * w + r_;
            const float v0 = s[0][reg] + Rs[w][r_][15 - r_ + m];
            const float v1 = s[1][reg] + Rs[w][r_][31 - r_ + m];
            const float p0 = (j0 + m      > i_) ? 0.f : __expf(v0);
            const float p1 = (j0 + m + 16 > i_) ? 0.f : __expf(v1);
            lsum[reg] += p0 + p1;
            Ps[w][r_][m]      = f2b(p0);
            Ps[w][r_][m + 16] = f2b(p1);
        }

        // O += P @ V
        bf16x8 pa = *(const bf16x8*)&Ps[w][m][qd * 8];
#pragma unroll
        for (int vt = 0; vt < 4; vt++) {
            bf16x8 bv = *(const bf16x8*)&Vt[16 * vt + m][qd * 8];
            o[vt] = __builtin_amdgcn_mfma_f32_16x16x32_bf16(pa, bv, o[vt], 0, 0, 0);
        }
    }

    // reduce l across the 16 lanes of each quad-group; epilogue
#pragma unroll
    for (int reg = 0; reg < 4; reg++) {
        float l = lsum[reg];
#pragma unroll
        for (int off = 1; off < 16; off <<= 1) l += __shfl_xor(l, off);
        const int r_ = qd * 4 + reg;
        const int i_ = i0 + 16 * w + r_;
        const bool pad = (mask[bb * TT + i_] == 0);
        const float inv = 1.0f / l;
        const size_t rowbase = ((size_t)bb * TT + hh * 64 + (i_ >> 4)) * EE + (i_ & 15) * 64;
#pragma unroll
        for (int vt = 0; vt < 4; vt++) {
            const int d_ = 16 * vt + m;
            float val = pad ? vmean[bh * SS + d_] : o[vt][reg] * inv;
            attn[rowbase + d_] = f2b(val);
        }
    }
}

// ---------------------------------------------------------------------------
// Kernel 4: MFMA bf16 GEMM  out = M @ Wo16^T + bo  (unchanged from R9)
// ---------------------------------------------------------------------------
__global__ __launch_bounds__(256) void outproj_kernel(
    const ushort_t* __restrict__ A, const ushort_t* __restrict__ Wo,
    const float* __restrict__ bo, float* __restrict__ out)
{
    __shared__ __align__(16) ushort_t As[128][36];
    __shared__ __align__(16) ushort_t Bs[128][36];

    const int tid  = threadIdx.x;
    const int lane = tid & 63;
    const int w    = tid >> 6;
    const int m    = lane & 15;
    const int qd   = lane >> 4;
    const int wrow = (w & 1) * 64;
    const int wcol = (w >> 1) * 64;
    const int o0   = blockIdx.x * 128;
    const int n0   = blockIdx.y * 128;

    f32x4 acc[4][4];
#pragma unroll
    for (int rt = 0; rt < 4; rt++)
#pragma unroll
        for (int ct = 0; ct < 4; ct++) acc[rt][ct] = {0.f, 0.f, 0.f, 0.f};

    for (int k0 = 0; k0 < 1024; k0 += 32) {
        __syncthreads();
#pragma unroll
        for (int l = 0; l < 2; l++) {
            const int idx = tid + 256 * l;
            const int row = idx >> 2;
            const int sub = idx & 3;
            *(uint4*)&As[row][sub * 8] =
                *(const uint4*)&A[(size_t)(n0 + row) * 1024 + k0 + sub * 8];
            *(uint4*)&Bs[row][sub * 8] =
                *(const uint4*)&Wo[(size_t)(o0 + row) * 1024 + k0 + sub * 8];
        }
        __syncthreads();

        bf16x8 af[4], bf[4];
#pragma unroll
        for (int rt = 0; rt < 4; rt++)
            af[rt] = *(const bf16x8*)&As[wrow + rt * 16 + m][qd * 8];
#pragma unroll
        for (int ct = 0; ct < 4; ct++)
            bf[ct] = *(const bf16x8*)&Bs[wcol + ct * 16 + m][qd * 8];
#pragma unroll
        for (int rt = 0; rt < 4; rt++)
#pragma unroll
            for (int ct = 0; ct < 4; ct++)
                acc[rt][ct] = __builtin_amdgcn_mfma_f32_16x16x32_bf16(
                    af[rt], bf[ct], acc[rt][ct], 0, 0, 0);
    }

#pragma unroll
    for (int rt = 0; rt < 4; rt++) {
#pragma unroll
        for (int ct = 0; ct < 4; ct++) {
            const int oc = o0 + wcol + ct * 16 + m;
            const float bias = bo[oc];
#pragma unroll
            for (int reg = 0; reg < 4; reg++) {
                const int n = n0 + wrow + rt * 16 + qd * 4 + reg;
                out[(size_t)n * EE + oc] = acc[rt][ct][reg] + bias;
            }
        }
    }
}

// ---------------------------------------------------------------------------
// Launcher.  ws (ushort): q16|k16|v16 (4M each) | er16 (1M) | wo16 (1M)
//            | M16 (4M) | vmean f32
// ---------------------------------------------------------------------------
extern "C" void kernel_launch(void* const* d_in, const int* in_sizes, int n_in,
                              void* d_out, int out_size, void* d_ws, size_t ws_size,
                              hipStream_t stream)
{
    const float* x    = (const float*)d_in[0];
    const int*   mask = (const int*)d_in[1];
    const float* Wq   = (const float*)d_in[2];
    const float* Wk   = (const float*)d_in[3];
    const float* Wv   = (const float*)d_in[4];
    const float* Er   = (const float*)d_in[5];
    const float* Wo   = (const float*)d_in[6];
    const float* bo   = (const float*)d_in[7];
    float* out = (float*)d_out;

    const size_t QKV = (size_t)BB * HH * TT * SS;
    const int    nEr = HH * TT * SS;
    const int    nWo = EE * EE;
    ushort_t* q16   = (ushort_t*)d_ws;
    ushort_t* k16   = q16 + QKV;
    ushort_t* v16   = k16 + QKV;
    ushort_t* er16  = v16 + QKV;
    ushort_t* wo16  = er16 + nEr;
    ushort_t* M16   = wo16 + nWo;
    float*    vmean = (float*)(M16 + QKV);

    cvt_kernel<<<dim3(4096), 256, 0, stream>>>(Er, er16, nEr);
    cvt_kernel<<<dim3(4096), 256, 0, stream>>>(Wo, wo16, nWo);
    qkv_kernel<<<dim3(BB * TT / 128, HH), 256, 0, stream>>>(x, Wq, Wk, Wv, q16, k16, v16);
    vmean_kernel<<<dim3(BB * HH), 256, 0, stream>>>(v16, vmean);
    attn_kernel<<<dim3(16, BB * HH), 256, 0, stream>>>(q16, k16, v16, er16, mask, vmean, M16);
    outproj_kernel<<<dim3(EE / 128, BB * TT / 128), 256, 0, stream>>>(M16, wo16, bo, out);
}

// Round 11
// 236.282 us; speedup vs baseline: 6.6490x; 1.2329x over previous
//
#include <hip/hip_runtime.h>
#include <hip/hip_bf16.h>
#include <math.h>
#include <stdint.h>

#define BB 4
#define TT 1024
#define EE 1024
#define HH 16
#define SS 64

typedef unsigned short ushort_t;
typedef __attribute__((ext_vector_type(8))) short bf16x8;
typedef __attribute__((ext_vector_type(8))) unsigned short u16x8;
typedef __attribute__((ext_vector_type(4))) unsigned short u16x4;
typedef __attribute__((ext_vector_type(4))) float f32x4;

__device__ __forceinline__ float b2f(ushort_t u) {
    union { float f; uint32_t i; } c;
    c.i = ((uint32_t)u) << 16;
    return c.f;
}
__device__ __forceinline__ ushort_t f2b(float f) {
    __hip_bfloat16 h = __float2bfloat16(f);
    return *(ushort_t*)&h;
}

// ---------------------------------------------------------------------------
// Kernel 0: fused fp32 -> bf16 converter for Er (na) then Wo (nb)
// ---------------------------------------------------------------------------
__global__ __launch_bounds__(256) void cvt2_kernel(
    const float* __restrict__ a, ushort_t* __restrict__ da, int na,
    const float* __restrict__ b, ushort_t* __restrict__ db, int nb)
{
    const int i = blockIdx.x * 256 + threadIdx.x;
    if (i < na) da[i] = f2b(a[i]);
    else {
        const int j = i - na;
        if (j < nb) db[j] = f2b(b[j]);
    }
}

// ---------------------------------------------------------------------------
// Kernel 1: MFMA q/k/v projection (verified R10).  Block = (128 t, one head).
// ---------------------------------------------------------------------------
__global__ __launch_bounds__(256) void qkv_kernel(
    const float* __restrict__ x, const float* __restrict__ Wq,
    const float* __restrict__ Wk, const float* __restrict__ Wv,
    ushort_t* __restrict__ q, ushort_t* __restrict__ k, ushort_t* __restrict__ v)
{
    __shared__ __align__(16) ushort_t Xs[128][72];
    __shared__ __align__(16) ushort_t Wl[3][64][72];

    const int tid  = threadIdx.x;
    const int lane = tid & 63;
    const int w    = tid >> 6;
    const int m    = lane & 15;
    const int qd   = lane >> 4;
    const int n0   = blockIdx.x * 128;
    const int hh   = blockIdx.y;
    const int bb   = n0 >> 10;

#pragma unroll
    for (int l = 0; l < 8; l++) {
        const int idx = tid + 256 * l;
        const int row = idx >> 4;
        const int c4  = idx & 15;
        const float4 xv = *(const float4*)&x[(size_t)(n0 + row) * 1024 + hh * 64 + c4 * 4];
        u16x4 o4 = { f2b(xv.x), f2b(xv.y), f2b(xv.z), f2b(xv.w) };
        *(u16x4*)&Xs[row][c4 * 4] = o4;
    }
#pragma unroll
    for (int l = 0; l < 12; l++) {
        const int idx = tid + 256 * l;
        const int mo  = idx >> 10;
        const int r   = (idx >> 4) & 63;
        const int c4  = idx & 15;
        const float* W = (mo == 0) ? Wq : (mo == 1) ? Wk : Wv;
        const float4 wv = *(const float4*)&W[r * 64 + c4 * 4];
        u16x4 o4 = { f2b(wv.x), f2b(wv.y), f2b(wv.z), f2b(wv.w) };
        *(u16x4*)&Wl[mo][r][c4 * 4] = o4;
    }
    __syncthreads();

    f32x4 acc[2][3][4];
#pragma unroll
    for (int rt = 0; rt < 2; rt++)
#pragma unroll
        for (int mo = 0; mo < 3; mo++)
#pragma unroll
            for (int ct = 0; ct < 4; ct++) acc[rt][mo][ct] = {0.f, 0.f, 0.f, 0.f};

#pragma unroll
    for (int ks = 0; ks < 2; ks++) {
        bf16x8 af[2];
#pragma unroll
        for (int rt = 0; rt < 2; rt++)
            af[rt] = *(const bf16x8*)&Xs[32 * w + 16 * rt + m][ks * 32 + qd * 8];
#pragma unroll
        for (int mo = 0; mo < 3; mo++)
#pragma unroll
            for (int ct = 0; ct < 4; ct++) {
                bf16x8 bw = *(const bf16x8*)&Wl[mo][ct * 16 + m][ks * 32 + qd * 8];
#pragma unroll
                for (int rt = 0; rt < 2; rt++)
                    acc[rt][mo][ct] = __builtin_amdgcn_mfma_f32_16x16x32_bf16(
                        af[rt], bw, acc[rt][mo][ct], 0, 0, 0);
            }
    }

    const size_t obase = ((size_t)bb * HH + hh) * TT;
#pragma unroll
    for (int mo = 0; mo < 3; mo++) {
        ushort_t* dst = (mo == 0) ? q : (mo == 1) ? k : v;
        const float sc = (mo == 1) ? 0.03125f : 1.0f;
#pragma unroll
        for (int rt = 0; rt < 2; rt++)
#pragma unroll
            for (int reg = 0; reg < 4; reg++) {
                const int t = (n0 & 1023) + 32 * w + 16 * rt + qd * 4 + reg;
#pragma unroll
                for (int ct = 0; ct < 4; ct++)
                    dst[(obase + t) * SS + ct * 16 + m] = f2b(acc[rt][mo][ct][reg] * sc);
            }
    }
}

// ---------------------------------------------------------------------------
// Kernel 2: vmean[b,h,d] from bf16 v
// ---------------------------------------------------------------------------
__global__ __launch_bounds__(256) void vmean_kernel(
    const ushort_t* __restrict__ v, float* __restrict__ vmean)
{
    const int bh  = blockIdx.x;
    const int tid = threadIdx.x;
    const int d   = tid & 63;
    const int jg  = tid >> 6;
    const ushort_t* vb = v + (size_t)bh * TT * SS;
    float p = 0.f;
    for (int j = jg; j < TT; j += 4) p += b2f(vb[j * SS + d]);
    __shared__ float red[4][64];
    red[jg][d] = p;
    __syncthreads();
    if (jg == 0)
        vmean[bh * SS + d] = (red[0][d] + red[1][d] + red[2][d] + red[3][d]) * (1.0f / TT);
}

// ---------------------------------------------------------------------------
// Kernel 3: MFMA bf16 flash attention.
//  - grid (bh, i0) for per-CU load balance
//  - register double-buffered K/V/Es staging (prefetch j0+32 during j0)
//  - skew gather via intra-quad __shfl (no Rs scratch -> 36.0 KB LDS, 4 blk/CU)
//  - Vt in chunk-major [4][64][8] layout (conflict-free b128 staging writes)
// Output: scrambled bf16 M[b, 64h + (t>>4), 64*(t&15) + s]
// ---------------------------------------------------------------------------
__global__ __launch_bounds__(256) void attn_kernel(
    const ushort_t* __restrict__ q, const ushort_t* __restrict__ k,
    const ushort_t* __restrict__ v, const ushort_t* __restrict__ er,
    const int* __restrict__ mask, const float* __restrict__ vmean,
    ushort_t* __restrict__ attn)
{
    __shared__ __align__(16) ushort_t Qs[64][72];
    __shared__ __align__(16) ushort_t Ks[32][72];
    __shared__ __align__(16) ushort_t Vt4[4][64][8];   // [j-chunk][d][j-sub]
    __shared__ __align__(16) ushort_t Es[96][72];      // ring buffer
    __shared__ __align__(16) ushort_t Ps[4][16][40];

    const int tid  = threadIdx.x;
    const int lane = tid & 63;
    const int w    = tid >> 6;
    const int m    = lane & 15;
    const int qd   = lane >> 4;
    const int bh   = blockIdx.x;
    const int bb   = bh >> 4;
    const int hh   = bh & 15;
    const int i0   = blockIdx.y * 64;

    const ushort_t* qb = q + (size_t)bh * TT * SS;
    const ushort_t* kb = k + (size_t)bh * TT * SS;
    const ushort_t* vb = v + (size_t)bh * TT * SS;
    const ushort_t* eb = er + (size_t)hh * TT * SS;
    const int l0 = 960 - i0;

    // prologue: Q (64x64) and Es ring slots 0..63 (l0..l0+63)
    for (int c = tid; c < 512; c += 256) {
        int row = c >> 3, sub = c & 7;
        *(uint4*)&Qs[row][sub * 8] = ((const uint4*)qb)[(size_t)(i0 + row) * 8 + sub];
    }
    for (int c = tid; c < 512; c += 256) {
        int row = c >> 3, sub = c & 7;
        int l = l0 + row;
        uint4 val = {0u, 0u, 0u, 0u};
        if (l <= 1023) val = ((const uint4*)eb)[(size_t)l * 8 + sub];
        *(uint4*)&Es[row][sub * 8] = val;
    }

    // register prefetch lanes
    const int krow = tid >> 3, ksub = tid & 7;   // K/Es staging: 32 rows x 8 subs
    const int vd   = tid & 63, vjh = tid >> 6;   // V staging: 64 d x 4 chunks
    uint4 kreg, ereg;
    u16x8 vreg;

    // prefetch for j0 = 0 (K rows 0..31, V j 0..31, Es l0+64..l0+95)
    {
        kreg = ((const uint4*)kb)[(size_t)krow * 8 + ksub];
#pragma unroll
        for (int jj = 0; jj < 8; jj++)
            vreg[jj] = vb[(size_t)(vjh * 8 + jj) * SS + vd];
        const int l = l0 + 64 + krow;
        ereg = (uint4){0u, 0u, 0u, 0u};
        if (l <= 1023) ereg = ((const uint4*)eb)[(size_t)l * 8 + ksub];
    }
    __syncthreads();

    bf16x8 aq[2];
#pragma unroll
    for (int ks = 0; ks < 2; ks++)
        aq[ks] = *(const bf16x8*)&Qs[16 * w + m][ks * 32 + qd * 8];

    f32x4 o[4];
#pragma unroll
    for (int vt = 0; vt < 4; vt++) o[vt] = {0.f, 0.f, 0.f, 0.f};
    float lsum[4] = {0.f, 0.f, 0.f, 0.f};

    const int ow = 48 - 16 * w;
    const int srcbase = lane & 48;

    for (int j0 = 0; j0 <= i0 + 32; j0 += 32) {
        // write phase: regs -> LDS
        *(uint4*)&Ks[krow][ksub * 8] = kreg;
        *(u16x8*)&Vt4[vjh][vd][0] = vreg;
        {
            const int slot = (64 + j0) % 96 + krow;
            *(uint4*)&Es[slot][ksub * 8] = ereg;
        }
        __syncthreads();

        // prefetch next tile while computing this one
        if (j0 <= i0) {
            const int jn = j0 + 32;
            kreg = ((const uint4*)kb)[(size_t)(jn + krow) * 8 + ksub];
#pragma unroll
            for (int jj = 0; jj < 8; jj++)
                vreg[jj] = vb[(size_t)(jn + vjh * 8 + jj) * SS + vd];
            const int l = l0 + 64 + jn + krow;
            ereg = (uint4){0u, 0u, 0u, 0u};
            if (l <= 1023) ereg = ((const uint4*)eb)[(size_t)l * 8 + ksub];
        }

        // S = Q @ K^T
        f32x4 s[2];
#pragma unroll
        for (int ct = 0; ct < 2; ct++) {
            s[ct] = {0.f, 0.f, 0.f, 0.f};
#pragma unroll
            for (int ks = 0; ks < 2; ks++) {
                bf16x8 bk = *(const bf16x8*)&Ks[16 * ct + m][ks * 32 + qd * 8];
                s[ct] = __builtin_amdgcn_mfma_f32_16x16x32_bf16(aq[ks], bk, s[ct], 0, 0, 0);
            }
        }
        // R tiles = Q @ Es_band^T (ring-indexed), kept in registers
        f32x4 r[3];
#pragma unroll
        for (int rt = 0; rt < 3; rt++) {
            const int row0 = (ow + 16 * rt + j0) % 96;
            r[rt] = {0.f, 0.f, 0.f, 0.f};
#pragma unroll
            for (int ks = 0; ks < 2; ks++) {
                bf16x8 be = *(const bf16x8*)&Es[row0 + m][ks * 32 + qd * 8];
                r[rt] = __builtin_amdgcn_mfma_f32_16x16x32_bf16(aq[ks], be, r[rt], 0, 0, 0);
            }
        }

        // skew gather via intra-quad shuffles + fixed-max softmax
#pragma unroll
        for (int reg = 0; reg < 4; reg++) {
            const int r_ = qd * 4 + reg;
            const int i_ = i0 + 16 * w + r_;
            const int base = 15 - r_ + m;               // gcol for ct=0, in [0,30]
            const int src  = srcbase | (base & 15);
            const float c0 = __shfl(r[0][reg], src);
            const float c1 = __shfl(r[1][reg], src);
            const float c2 = __shfl(r[2][reg], src);
            const float e0 = (base < 16) ? c0 : c1;
            const float e1 = (base < 16) ? c1 : c2;     // gcol+16 in [16,46]
            const float v0 = s[0][reg] + e0;
            const float v1 = s[1][reg] + e1;
            const float p0 = (j0 + m      > i_) ? 0.f : __expf(v0);
            const float p1 = (j0 + m + 16 > i_) ? 0.f : __expf(v1);
            lsum[reg] += p0 + p1;
            Ps[w][r_][m]      = f2b(p0);
            Ps[w][r_][m + 16] = f2b(p1);
        }

        // O += P @ V
        bf16x8 pa = *(const bf16x8*)&Ps[w][m][qd * 8];
#pragma unroll
        for (int vt = 0; vt < 4; vt++) {
            bf16x8 bv = *(const bf16x8*)&Vt4[qd][16 * vt + m][0];
            o[vt] = __builtin_amdgcn_mfma_f32_16x16x32_bf16(pa, bv, o[vt], 0, 0, 0);
        }
        __syncthreads();
    }

    // reduce l across quad-group lanes; epilogue with scrambled bf16 store
#pragma unroll
    for (int reg = 0; reg < 4; reg++) {
        float l = lsum[reg];
#pragma unroll
        for (int off = 1; off < 16; off <<= 1) l += __shfl_xor(l, off);
        const int r_ = qd * 4 + reg;
        const int i_ = i0 + 16 * w + r_;
        const bool pad = (mask[bb * TT + i_] == 0);
        const float inv = 1.0f / l;
        const size_t rowbase = ((size_t)bb * TT + hh * 64 + (i_ >> 4)) * EE + (i_ & 15) * 64;
#pragma unroll
        for (int vt = 0; vt < 4; vt++) {
            const int d_ = 16 * vt + m;
            float val = pad ? vmean[bh * SS + d_] : o[vt][reg] * inv;
            attn[rowbase + d_] = f2b(val);
        }
    }
}

// ---------------------------------------------------------------------------
// Kernel 4: MFMA bf16 GEMM  out = M @ Wo16^T + bo  (unchanged)
// ---------------------------------------------------------------------------
__global__ __launch_bounds__(256) void outproj_kernel(
    const ushort_t* __restrict__ A, const ushort_t* __restrict__ Wo,
    const float* __restrict__ bo, float* __restrict__ out)
{
    __shared__ __align__(16) ushort_t As[128][36];
    __shared__ __align__(16) ushort_t Bs[128][36];

    const int tid  = threadIdx.x;
    const int lane = tid & 63;
    const int w    = tid >> 6;
    const int m    = lane & 15;
    const int qd   = lane >> 4;
    const int wrow = (w & 1) * 64;
    const int wcol = (w >> 1) * 64;
    const int o0   = blockIdx.x * 128;
    const int n0   = blockIdx.y * 128;

    f32x4 acc[4][4];
#pragma unroll
    for (int rt = 0; rt < 4; rt++)
#pragma unroll
        for (int ct = 0; ct < 4; ct++) acc[rt][ct] = {0.f, 0.f, 0.f, 0.f};

    for (int k0 = 0; k0 < 1024; k0 += 32) {
        __syncthreads();
#pragma unroll
        for (int l = 0; l < 2; l++) {
            const int idx = tid + 256 * l;
            const int row = idx >> 2;
            const int sub = idx & 3;
            *(uint4*)&As[row][sub * 8] =
                *(const uint4*)&A[(size_t)(n0 + row) * 1024 + k0 + sub * 8];
            *(uint4*)&Bs[row][sub * 8] =
                *(const uint4*)&Wo[(size_t)(o0 + row) * 1024 + k0 + sub * 8];
        }
        __syncthreads();

        bf16x8 af[4], bf[4];
#pragma unroll
        for (int rt = 0; rt < 4; rt++)
            af[rt] = *(const bf16x8*)&As[wrow + rt * 16 + m][qd * 8];
#pragma unroll
        for (int ct = 0; ct < 4; ct++)
            bf[ct] = *(const bf16x8*)&Bs[wcol + ct * 16 + m][qd * 8];
#pragma unroll
        for (int rt = 0; rt < 4; rt++)
#pragma unroll
            for (int ct = 0; ct < 4; ct++)
                acc[rt][ct] = __builtin_amdgcn_mfma_f32_16x16x32_bf16(
                    af[rt], bf[ct], acc[rt][ct], 0, 0, 0);
    }

#pragma unroll
    for (int rt = 0; rt < 4; rt++) {
#pragma unroll
        for (int ct = 0; ct < 4; ct++) {
            const int oc = o0 + wcol + ct * 16 + m;
            const float bias = bo[oc];
#pragma unroll
            for (int reg = 0; reg < 4; reg++) {
                const int n = n0 + wrow + rt * 16 + qd * 4 + reg;
                out[(size_t)n * EE + oc] = acc[rt][ct][reg] + bias;
            }
        }
    }
}

// ---------------------------------------------------------------------------
// Launcher.  ws (ushort): q16|k16|v16 (4M each) | er16 (1M) | wo16 (1M)
//            | M16 (4M) | vmean f32
// ---------------------------------------------------------------------------
extern "C" void kernel_launch(void* const* d_in, const int* in_sizes, int n_in,
                              void* d_out, int out_size, void* d_ws, size_t ws_size,
                              hipStream_t stream)
{
    const float* x    = (const float*)d_in[0];
    const int*   mask = (const int*)d_in[1];
    const float* Wq   = (const float*)d_in[2];
    const float* Wk   = (const float*)d_in[3];
    const float* Wv   = (const float*)d_in[4];
    const float* Er   = (const float*)d_in[5];
    const float* Wo   = (const float*)d_in[6];
    const float* bo   = (const float*)d_in[7];
    float* out = (float*)d_out;

    const size_t QKV = (size_t)BB * HH * TT * SS;
    const int    nEr = HH * TT * SS;
    const int    nWo = EE * EE;
    ushort_t* q16   = (ushort_t*)d_ws;
    ushort_t* k16   = q16 + QKV;
    ushort_t* v16   = k16 + QKV;
    ushort_t* er16  = v16 + QKV;
    ushort_t* wo16  = er16 + nEr;
    ushort_t* M16   = wo16 + nWo;
    float*    vmean = (float*)(M16 + QKV);

    cvt2_kernel<<<dim3((nEr + nWo) / 256), 256, 0, stream>>>(Er, er16, nEr, Wo, wo16, nWo);
    qkv_kernel<<<dim3(BB * TT / 128, HH), 256, 0, stream>>>(x, Wq, Wk, Wv, q16, k16, v16);
    vmean_kernel<<<dim3(BB * HH), 256, 0, stream>>>(v16, vmean);
    attn_kernel<<<dim3(BB * HH, TT / 64), 256, 0, stream>>>(q16, k16, v16, er16, mask, vmean, M16);
    outproj_kernel<<<dim3(EE / 128, BB * TT / 128), 256, 0, stream>>>(M16, wo16, bo, out);
}

// Round 12
// 175.583 us; speedup vs baseline: 8.9476x; 1.3457x over previous
//
#include <hip/hip_runtime.h>
#include <hip/hip_bf16.h>
#include <math.h>
#include <stdint.h>

#define BB 4
#define TT 1024
#define EE 1024
#define HH 16
#define SS 64

typedef unsigned short ushort_t;
typedef __attribute__((ext_vector_type(8))) short bf16x8;
typedef __attribute__((ext_vector_type(8))) unsigned short u16x8;
typedef __attribute__((ext_vector_type(4))) unsigned short u16x4;
typedef __attribute__((ext_vector_type(4))) float f32x4;

__device__ __forceinline__ float b2f(ushort_t u) {
    union { float f; uint32_t i; } c;
    c.i = ((uint32_t)u) << 16;
    return c.f;
}
__device__ __forceinline__ ushort_t f2b(float f) {
    __hip_bfloat16 h = __float2bfloat16(f);
    return *(ushort_t*)&h;
}

// ---------------------------------------------------------------------------
// Kernel 0: fused fp32 -> bf16 converter, 4 elems/thread (Er then Wo)
// ---------------------------------------------------------------------------
__global__ __launch_bounds__(256) void cvt2_kernel(
    const float* __restrict__ a, ushort_t* __restrict__ da, int na,
    const float* __restrict__ b, ushort_t* __restrict__ db, int nb)
{
    const int i4 = (blockIdx.x * 256 + threadIdx.x) * 4;
    if (i4 < na) {
        const float4 xv = *(const float4*)&a[i4];
        u16x4 o4 = { f2b(xv.x), f2b(xv.y), f2b(xv.z), f2b(xv.w) };
        *(u16x4*)&da[i4] = o4;
    } else {
        const int j4 = i4 - na;
        if (j4 < nb) {
            const float4 xv = *(const float4*)&b[j4];
            u16x4 o4 = { f2b(xv.x), f2b(xv.y), f2b(xv.z), f2b(xv.w) };
            *(u16x4*)&db[j4] = o4;
        }
    }
}

// ---------------------------------------------------------------------------
// Kernel 1: MFMA q/k/v projection + fused vmean accumulation.
// Block = (128 t, one head).  vmean gets the RAW column sum of fp32 v accs
// (attn scales by 1/1024); vmean must be zeroed before launch.
// ---------------------------------------------------------------------------
__global__ __launch_bounds__(256) void qkv_kernel(
    const float* __restrict__ x, const float* __restrict__ Wq,
    const float* __restrict__ Wk, const float* __restrict__ Wv,
    ushort_t* __restrict__ q, ushort_t* __restrict__ k, ushort_t* __restrict__ v,
    float* __restrict__ vmean)
{
    __shared__ __align__(16) ushort_t Xs[128][72];
    __shared__ __align__(16) ushort_t Wl[3][64][72];

    const int tid  = threadIdx.x;
    const int lane = tid & 63;
    const int w    = tid >> 6;
    const int m    = lane & 15;
    const int qd   = lane >> 4;
    const int n0   = blockIdx.x * 128;
    const int hh   = blockIdx.y;
    const int bb   = n0 >> 10;

#pragma unroll
    for (int l = 0; l < 8; l++) {
        const int idx = tid + 256 * l;
        const int row = idx >> 4;
        const int c4  = idx & 15;
        const float4 xv = *(const float4*)&x[(size_t)(n0 + row) * 1024 + hh * 64 + c4 * 4];
        u16x4 o4 = { f2b(xv.x), f2b(xv.y), f2b(xv.z), f2b(xv.w) };
        *(u16x4*)&Xs[row][c4 * 4] = o4;
    }
#pragma unroll
    for (int l = 0; l < 12; l++) {
        const int idx = tid + 256 * l;
        const int mo  = idx >> 10;
        const int r   = (idx >> 4) & 63;
        const int c4  = idx & 15;
        const float* W = (mo == 0) ? Wq : (mo == 1) ? Wk : Wv;
        const float4 wv = *(const float4*)&W[r * 64 + c4 * 4];
        u16x4 o4 = { f2b(wv.x), f2b(wv.y), f2b(wv.z), f2b(wv.w) };
        *(u16x4*)&Wl[mo][r][c4 * 4] = o4;
    }
    __syncthreads();

    f32x4 acc[2][3][4];
#pragma unroll
    for (int rt = 0; rt < 2; rt++)
#pragma unroll
        for (int mo = 0; mo < 3; mo++)
#pragma unroll
            for (int ct = 0; ct < 4; ct++) acc[rt][mo][ct] = {0.f, 0.f, 0.f, 0.f};

#pragma unroll
    for (int ks = 0; ks < 2; ks++) {
        bf16x8 af[2];
#pragma unroll
        for (int rt = 0; rt < 2; rt++)
            af[rt] = *(const bf16x8*)&Xs[32 * w + 16 * rt + m][ks * 32 + qd * 8];
#pragma unroll
        for (int mo = 0; mo < 3; mo++)
#pragma unroll
            for (int ct = 0; ct < 4; ct++) {
                bf16x8 bw = *(const bf16x8*)&Wl[mo][ct * 16 + m][ks * 32 + qd * 8];
#pragma unroll
                for (int rt = 0; rt < 2; rt++)
                    acc[rt][mo][ct] = __builtin_amdgcn_mfma_f32_16x16x32_bf16(
                        af[rt], bw, acc[rt][mo][ct], 0, 0, 0);
            }
    }

    const size_t obase = ((size_t)bb * HH + hh) * TT;
#pragma unroll
    for (int mo = 0; mo < 3; mo++) {
        ushort_t* dst = (mo == 0) ? q : (mo == 1) ? k : v;
        const float sc = (mo == 1) ? 0.03125f : 1.0f;
#pragma unroll
        for (int rt = 0; rt < 2; rt++)
#pragma unroll
            for (int reg = 0; reg < 4; reg++) {
                const int t = (n0 & 1023) + 32 * w + 16 * rt + qd * 4 + reg;
#pragma unroll
                for (int ct = 0; ct < 4; ct++)
                    dst[(obase + t) * SS + ct * 16 + m] = f2b(acc[rt][mo][ct][reg] * sc);
            }
    }

    // fused vmean: per-lane 8-row partial -> quad reduce -> one atomic/wave/col
#pragma unroll
    for (int ct = 0; ct < 4; ct++) {
        float s = 0.f;
#pragma unroll
        for (int rt = 0; rt < 2; rt++)
#pragma unroll
            for (int reg = 0; reg < 4; reg++) s += acc[rt][2][ct][reg];
        s += __shfl_xor(s, 16);
        s += __shfl_xor(s, 32);
        if (qd == 0)
            atomicAdd(&vmean[(bb * HH + hh) * SS + ct * 16 + m], s);
    }
}

// ---------------------------------------------------------------------------
// Kernel 3: MFMA bf16 flash attention (verified R11 structure).
// vmean is a RAW sum here -> scale by 1/1024 at use.
// ---------------------------------------------------------------------------
__global__ __launch_bounds__(256) void attn_kernel(
    const ushort_t* __restrict__ q, const ushort_t* __restrict__ k,
    const ushort_t* __restrict__ v, const ushort_t* __restrict__ er,
    const int* __restrict__ mask, const float* __restrict__ vmean,
    ushort_t* __restrict__ attn)
{
    __shared__ __align__(16) ushort_t Qs[64][72];
    __shared__ __align__(16) ushort_t Ks[32][72];
    __shared__ __align__(16) ushort_t Vt4[4][64][8];
    __shared__ __align__(16) ushort_t Es[96][72];
    __shared__ __align__(16) ushort_t Ps[4][16][40];

    const int tid  = threadIdx.x;
    const int lane = tid & 63;
    const int w    = tid >> 6;
    const int m    = lane & 15;
    const int qd   = lane >> 4;
    const int bh   = blockIdx.x;
    const int bb   = bh >> 4;
    const int hh   = bh & 15;
    const int i0   = blockIdx.y * 64;

    const ushort_t* qb = q + (size_t)bh * TT * SS;
    const ushort_t* kb = k + (size_t)bh * TT * SS;
    const ushort_t* vb = v + (size_t)bh * TT * SS;
    const ushort_t* eb = er + (size_t)hh * TT * SS;
    const int l0 = 960 - i0;

    for (int c = tid; c < 512; c += 256) {
        int row = c >> 3, sub = c & 7;
        *(uint4*)&Qs[row][sub * 8] = ((const uint4*)qb)[(size_t)(i0 + row) * 8 + sub];
    }
    for (int c = tid; c < 512; c += 256) {
        int row = c >> 3, sub = c & 7;
        int l = l0 + row;
        uint4 val = {0u, 0u, 0u, 0u};
        if (l <= 1023) val = ((const uint4*)eb)[(size_t)l * 8 + sub];
        *(uint4*)&Es[row][sub * 8] = val;
    }

    const int krow = tid >> 3, ksub = tid & 7;
    const int vd   = tid & 63, vjh = tid >> 6;
    uint4 kreg, ereg;
    u16x8 vreg;

    {
        kreg = ((const uint4*)kb)[(size_t)krow * 8 + ksub];
#pragma unroll
        for (int jj = 0; jj < 8; jj++)
            vreg[jj] = vb[(size_t)(vjh * 8 + jj) * SS + vd];
        const int l = l0 + 64 + krow;
        ereg = (uint4){0u, 0u, 0u, 0u};
        if (l <= 1023) ereg = ((const uint4*)eb)[(size_t)l * 8 + ksub];
    }
    __syncthreads();

    bf16x8 aq[2];
#pragma unroll
    for (int ks = 0; ks < 2; ks++)
        aq[ks] = *(const bf16x8*)&Qs[16 * w + m][ks * 32 + qd * 8];

    f32x4 o[4];
#pragma unroll
    for (int vt = 0; vt < 4; vt++) o[vt] = {0.f, 0.f, 0.f, 0.f};
    float lsum[4] = {0.f, 0.f, 0.f, 0.f};

    const int ow = 48 - 16 * w;
    const int srcbase = lane & 48;

    for (int j0 = 0; j0 <= i0 + 32; j0 += 32) {
        *(uint4*)&Ks[krow][ksub * 8] = kreg;
        *(u16x8*)&Vt4[vjh][vd][0] = vreg;
        {
            const int slot = (64 + j0) % 96 + krow;
            *(uint4*)&Es[slot][ksub * 8] = ereg;
        }
        __syncthreads();

        if (j0 <= i0) {
            const int jn = j0 + 32;
            kreg = ((const uint4*)kb)[(size_t)(jn + krow) * 8 + ksub];
#pragma unroll
            for (int jj = 0; jj < 8; jj++)
                vreg[jj] = vb[(size_t)(jn + vjh * 8 + jj) * SS + vd];
            const int l = l0 + 64 + jn + krow;
            ereg = (uint4){0u, 0u, 0u, 0u};
            if (l <= 1023) ereg = ((const uint4*)eb)[(size_t)l * 8 + ksub];
        }

        f32x4 s[2];
#pragma unroll
        for (int ct = 0; ct < 2; ct++) {
            s[ct] = {0.f, 0.f, 0.f, 0.f};
#pragma unroll
            for (int ks = 0; ks < 2; ks++) {
                bf16x8 bk = *(const bf16x8*)&Ks[16 * ct + m][ks * 32 + qd * 8];
                s[ct] = __builtin_amdgcn_mfma_f32_16x16x32_bf16(aq[ks], bk, s[ct], 0, 0, 0);
            }
        }
        f32x4 r[3];
#pragma unroll
        for (int rt = 0; rt < 3; rt++) {
            const int row0 = (ow + 16 * rt + j0) % 96;
            r[rt] = {0.f, 0.f, 0.f, 0.f};
#pragma unroll
            for (int ks = 0; ks < 2; ks++) {
                bf16x8 be = *(const bf16x8*)&Es[row0 + m][ks * 32 + qd * 8];
                r[rt] = __builtin_amdgcn_mfma_f32_16x16x32_bf16(aq[ks], be, r[rt], 0, 0, 0);
            }
        }

#pragma unroll
        for (int reg = 0; reg < 4; reg++) {
            const int r_ = qd * 4 + reg;
            const int i_ = i0 + 16 * w + r_;
            const int base = 15 - r_ + m;
            const int src  = srcbase | (base & 15);
            const float c0 = __shfl(r[0][reg], src);
            const float c1 = __shfl(r[1][reg], src);
            const float c2 = __shfl(r[2][reg], src);
            const float e0 = (base < 16) ? c0 : c1;
            const float e1 = (base < 16) ? c1 : c2;
            const float v0 = s[0][reg] + e0;
            const float v1 = s[1][reg] + e1;
            const float p0 = (j0 + m      > i_) ? 0.f : __expf(v0);
            const float p1 = (j0 + m + 16 > i_) ? 0.f : __expf(v1);
            lsum[reg] += p0 + p1;
            Ps[w][r_][m]      = f2b(p0);
            Ps[w][r_][m + 16] = f2b(p1);
        }

        bf16x8 pa = *(const bf16x8*)&Ps[w][m][qd * 8];
#pragma unroll
        for (int vt = 0; vt < 4; vt++) {
            bf16x8 bv = *(const bf16x8*)&Vt4[qd][16 * vt + m][0];
            o[vt] = __builtin_amdgcn_mfma_f32_16x16x32_bf16(pa, bv, o[vt], 0, 0, 0);
        }
        __syncthreads();
    }

#pragma unroll
    for (int reg = 0; reg < 4; reg++) {
        float l = lsum[reg];
#pragma unroll
        for (int off = 1; off < 16; off <<= 1) l += __shfl_xor(l, off);
        const int r_ = qd * 4 + reg;
        const int i_ = i0 + 16 * w + r_;
        const bool pad = (mask[bb * TT + i_] == 0);
        const float inv = 1.0f / l;
        const size_t rowbase = ((size_t)bb * TT + hh * 64 + (i_ >> 4)) * EE + (i_ & 15) * 64;
#pragma unroll
        for (int vt = 0; vt < 4; vt++) {
            const int d_ = 16 * vt + m;
            float val = pad ? vmean[bh * SS + d_] * (1.0f / 1024.0f)
                            : o[vt][reg] * inv;
            attn[rowbase + d_] = f2b(val);
        }
    }
}

// ---------------------------------------------------------------------------
// Kernel 4: MFMA bf16 GEMM  out = M @ Wo16^T + bo  (unchanged)
// ---------------------------------------------------------------------------
__global__ __launch_bounds__(256) void outproj_kernel(
    const ushort_t* __restrict__ A, const ushort_t* __restrict__ Wo,
    const float* __restrict__ bo, float* __restrict__ out)
{
    __shared__ __align__(16) ushort_t As[128][36];
    __shared__ __align__(16) ushort_t Bs[128][36];

    const int tid  = threadIdx.x;
    const int lane = tid & 63;
    const int w    = tid >> 6;
    const int m    = lane & 15;
    const int qd   = lane >> 4;
    const int wrow = (w & 1) * 64;
    const int wcol = (w >> 1) * 64;
    const int o0   = blockIdx.x * 128;
    const int n0   = blockIdx.y * 128;

    f32x4 acc[4][4];
#pragma unroll
    for (int rt = 0; rt < 4; rt++)
#pragma unroll
        for (int ct = 0; ct < 4; ct++) acc[rt][ct] = {0.f, 0.f, 0.f, 0.f};

    for (int k0 = 0; k0 < 1024; k0 += 32) {
        __syncthreads();
#pragma unroll
        for (int l = 0; l < 2; l++) {
            const int idx = tid + 256 * l;
            const int row = idx >> 2;
            const int sub = idx & 3;
            *(uint4*)&As[row][sub * 8] =
                *(const uint4*)&A[(size_t)(n0 + row) * 1024 + k0 + sub * 8];
            *(uint4*)&Bs[row][sub * 8] =
                *(const uint4*)&Wo[(size_t)(o0 + row) * 1024 + k0 + sub * 8];
        }
        __syncthreads();

        bf16x8 af[4], bf[4];
#pragma unroll
        for (int rt = 0; rt < 4; rt++)
            af[rt] = *(const bf16x8*)&As[wrow + rt * 16 + m][qd * 8];
#pragma unroll
        for (int ct = 0; ct < 4; ct++)
            bf[ct] = *(const bf16x8*)&Bs[wcol + ct * 16 + m][qd * 8];
#pragma unroll
        for (int rt = 0; rt < 4; rt++)
#pragma unroll
            for (int ct = 0; ct < 4; ct++)
                acc[rt][ct] = __builtin_amdgcn_mfma_f32_16x16x32_bf16(
                    af[rt], bf[ct], acc[rt][ct], 0, 0, 0);
    }

#pragma unroll
    for (int rt = 0; rt < 4; rt++) {
#pragma unroll
        for (int ct = 0; ct < 4; ct++) {
            const int oc = o0 + wcol + ct * 16 + m;
            const float bias = bo[oc];
#pragma unroll
            for (int reg = 0; reg < 4; reg++) {
                const int n = n0 + wrow + rt * 16 + qd * 4 + reg;
                out[(size_t)n * EE + oc] = acc[rt][ct][reg] + bias;
            }
        }
    }
}

// ---------------------------------------------------------------------------
// Launcher.  ws (ushort): q16|k16|v16 (4M each) | er16 (1M) | wo16 (1M)
//            | M16 (4M) | vmean f32 (4096)
// ---------------------------------------------------------------------------
extern "C" void kernel_launch(void* const* d_in, const int* in_sizes, int n_in,
                              void* d_out, int out_size, void* d_ws, size_t ws_size,
                              hipStream_t stream)
{
    const float* x    = (const float*)d_in[0];
    const int*   mask = (const int*)d_in[1];
    const float* Wq   = (const float*)d_in[2];
    const float* Wk   = (const float*)d_in[3];
    const float* Wv   = (const float*)d_in[4];
    const float* Er   = (const float*)d_in[5];
    const float* Wo   = (const float*)d_in[6];
    const float* bo   = (const float*)d_in[7];
    float* out = (float*)d_out;

    const size_t QKV = (size_t)BB * HH * TT * SS;
    const int    nEr = HH * TT * SS;
    const int    nWo = EE * EE;
    ushort_t* q16   = (ushort_t*)d_ws;
    ushort_t* k16   = q16 + QKV;
    ushort_t* v16   = k16 + QKV;
    ushort_t* er16  = v16 + QKV;
    ushort_t* wo16  = er16 + nEr;
    ushort_t* M16   = wo16 + nWo;
    float*    vmean = (float*)(M16 + QKV);

    hipMemsetAsync(vmean, 0, BB * HH * SS * sizeof(float), stream);
    cvt2_kernel<<<dim3((nEr + nWo) / 1024), 256, 0, stream>>>(Er, er16, nEr, Wo, wo16, nWo);
    qkv_kernel<<<dim3(BB * TT / 128, HH), 256, 0, stream>>>(x, Wq, Wk, Wv, q16, k16, v16, vmean);
    attn_kernel<<<dim3(BB * HH, TT / 64), 256, 0, stream>>>(q16, k16, v16, er16, mask, vmean, M16);
    outproj_kernel<<<dim3(EE / 128, BB * TT / 128), 256, 0, stream>>>(M16, wo16, bo, out);
}